// Round 6
// baseline (32122.565 us; speedup 1.0000x reference)
//
#include <hip/hip_runtime.h>
#include <math.h>

#define NB 8
#define NP 2048
#define KNN 20
#define CSTR 520          // padded row stride of the cat feature buffer (floats)
#define NEG 0.2f
// padded column layout: [x:0..3)[pad:3][x1:4..68)[x2:68..132)[x3:132..260)[x4:260..516)
// every slice start is a multiple of 4 floats (16B-aligned)

__device__ __forceinline__ float leaky(float x) { return x >= 0.0f ? x : NEG * x; }

// ---------------- transpose x (B,3,N) -> cat[:, :, 0:3], zero pad col 3 ----------------
__global__ void tx_kernel(const float* __restrict__ x, float* __restrict__ cat) {
    int i = blockIdx.x * blockDim.x + threadIdx.x;
    if (i >= NB * NP) return;
    int b = i / NP, n = i % NP;
    float* r = cat + (size_t)i * CSTR;
    r[0] = x[((size_t)b * 3 + 0) * NP + n];
    r[1] = x[((size_t)b * 3 + 1) * NP + n];
    r[2] = x[((size_t)b * 3 + 2) * NP + n];
    r[3] = 0.0f;
    r[516] = 0.f; r[517] = 0.f; r[518] = 0.f; r[519] = 0.f;
}

// ---------------- conv weights W (O, 2*Cin) -> Wyz (PC, 2*O): [Wd | Wc - Wd] ----------------
// padded channel q: q==3 -> zero row; q<3 -> c=q; q>3 -> c=q-1  (slice always starts at col 0)
__global__ void buildWyz(const float* __restrict__ W, float* __restrict__ Wyz,
                         int O, int Cin, int PC) {
    int i = blockIdx.x * blockDim.x + threadIdx.x;
    int N2 = 2 * O;
    if (i >= PC * N2) return;
    int q = i / N2, n = i - q * N2;
    float v = 0.0f;
    if (q != 3) {
        int c = (q < 3) ? q : q - 1;
        if (c < Cin) {
            int o = (n < O) ? n : n - O;
            float wd = W[(size_t)o * (2 * Cin) + c];
            v = (n < O) ? wd : (W[(size_t)o * (2 * Cin) + Cin + c] - wd);
        }
    }
    Wyz[i] = v;
}

// ---------------- W5 (1024, 515) -> padded transposed W5t (520, 1024) ----------------
__global__ void transposeW5(const float* __restrict__ W, float* __restrict__ Wt) {
    int i = blockIdx.x * blockDim.x + threadIdx.x;
    if (i >= 520 * 1024) return;
    int p = i >> 10, o = i & 1023;
    float v = 0.0f;
    if (p < 516 && p != 3) {
        int c = (p < 3) ? p : p - 1;
        v = W[(size_t)o * 515 + c];
    }
    Wt[i] = v;
}

// ---------------- squared norms of feature slice (padded C, pad col is zero) ----------------
__global__ void sqnorm_kernel(const float* __restrict__ cat, int off, int C, float* __restrict__ sq) {
    int i = blockIdx.x * blockDim.x + threadIdx.x;
    if (i >= NB * NP) return;
    const float* f = cat + (size_t)i * CSTR + off;
    float s = 0.f;
    for (int c = 0; c < C; c += 4) {
        float4 v = *reinterpret_cast<const float4*>(f + c);
        s += v.x * v.x + v.y * v.y + v.z * v.z + v.w * v.w;
    }
    sq[i] = s;
}

// ---------------- KNN v3: LDS-tiled distances, per-lane REGISTER dist array ----------------
// block = 256 threads = 4 waves; one query per wave; lane owns candidates j ≡ lane (mod 64):
// d[t] = dist(query, t*64+lane). No distL in LDS -> 35/18 KB LDS, 2x occupancy.
template <int C>
__global__ __launch_bounds__(256, 4) void knn2_kernel(const float* __restrict__ cat, int off,
                                                      const float* __restrict__ sq,
                                                      int* __restrict__ idxout) {
    constexpr int CG = C / 4;
    __shared__ float4 tile[CG][65];
    __shared__ float4 qf[4][CG];
    int wave = threadIdx.x >> 6, lane = threadIdx.x & 63;
    int q = blockIdx.x * 4 + wave;
    int b = q >> 11, n = q & (NP - 1);
    const float* base = cat + (size_t)b * NP * CSTR + off;

    for (int cg = lane; cg < CG; cg += 64)
        qf[wave][cg] = *reinterpret_cast<const float4*>(base + (size_t)n * CSTR + 4 * cg);
    float sqi = sq[q];

    float d[32];                         // statically indexed (loops fully unrolled)
    #pragma unroll
    for (int t = 0; t < 32; ++t) {
        __syncthreads();
        for (int e = threadIdx.x; e < 64 * CG; e += 256) {
            int j = e / CG, cg = e - j * CG;
            tile[cg][j] = *reinterpret_cast<const float4*>(base + (size_t)(t * 64 + j) * CSTR + 4 * cg);
        }
        __syncthreads();
        float dot = 0.f;
        #pragma unroll
        for (int cg = 0; cg < CG; ++cg) {
            float4 a = qf[wave][cg];      // broadcast
            float4 v = tile[cg][lane];    // lane-consecutive 16B
            dot += a.x * v.x + a.y * v.y + a.z * v.z + a.w * v.w;
        }
        d[t] = 2.f * dot - sqi - sq[b * NP + t * 64 + lane];
    }
    // selection: iterative argmax over register array; ascending j per lane, strict > keeps lowest
    for (int k = 0; k < KNN; ++k) {
        float bv = -INFINITY; int bj = 0x7fffffff;
        #pragma unroll
        for (int t = 0; t < 32; ++t) {
            if (d[t] > bv) { bv = d[t]; bj = t * 64 + lane; }
        }
        for (int s = 32; s; s >>= 1) {
            float ov = __shfl_xor(bv, s);
            int oj = __shfl_xor(bj, s);
            if (ov > bv || (ov == bv && oj < bj)) { bv = ov; bj = oj; }
        }
        if (lane == 0) idxout[(size_t)q * KNN + k] = bj;
        #pragma unroll
        for (int t = 0; t < 32; ++t)      // owner lane invalidates its slot (static indices)
            if (t * 64 + lane == bj) d[t] = -INFINITY;
    }
}

// ---------------- YZ GEMM: YZ[p][:] = cat[p][0:K] @ Wyz (K x N2) ----------------
// 16-row register blocking (pool_w5 pattern): 16 FMAs per W load, LDS broadcast reads.
template <int K, int NT>
__global__ __launch_bounds__(NT) void gemm_yz_kernel(const float* __restrict__ cat, int off,
                                                     const float* __restrict__ W, int N2,
                                                     float* __restrict__ YZ) {
    __shared__ float rows[16][K];
    int col = blockIdx.y * NT + threadIdx.x;
    const float* src = cat + (size_t)blockIdx.x * 16 * CSTR + off;
    for (int e = threadIdx.x; e < 16 * (K / 4); e += NT) {
        int r = e / (K / 4), cg = e - r * (K / 4);
        *reinterpret_cast<float4*>(&rows[r][4 * cg]) =
            *reinterpret_cast<const float4*>(src + (size_t)r * CSTR + 4 * cg);
    }
    __syncthreads();
    float acc[16];
    #pragma unroll
    for (int r = 0; r < 16; ++r) acc[r] = 0.f;
    for (int c = 0; c < K; c += 4) {
        float w0 = W[(size_t)(c + 0) * N2 + col];
        float w1 = W[(size_t)(c + 1) * N2 + col];
        float w2 = W[(size_t)(c + 2) * N2 + col];
        float w3 = W[(size_t)(c + 3) * N2 + col];
        #pragma unroll
        for (int r = 0; r < 16; ++r) {
            float4 rv = *reinterpret_cast<const float4*>(&rows[r][c]);
            acc[r] += rv.x * w0 + rv.y * w1 + rv.z * w2 + rv.w * w3;
        }
    }
    float* dst = YZ + (size_t)blockIdx.x * 16 * N2 + col;
    #pragma unroll
    for (int r = 0; r < 16; ++r) dst[(size_t)r * N2] = acc[r];
}

// ---------------- combine: out[p][o] = max_k leaky((Y[j_k][o] + Z[p][o])*s + b) ----------------
template <int O>
__global__ __launch_bounds__(256) void combine_kernel(const float* __restrict__ YZ, int N2,
                                                      const int* __restrict__ idx,
                                                      const float* __restrict__ g,
                                                      const float* __restrict__ bias,
                                                      float* __restrict__ cat, int outOff) {
    constexpr int PPB = 256 / O;
    int sub = threadIdx.x / O, o = threadIdx.x % O;
    int p = blockIdx.x * PPB + sub;
    int bbase = p & ~(NP - 1);             // batch-global row base for local neighbor ids
    const float bns = 1.0f / sqrtf(1.0f + 1e-5f);
    float s = g[o] * bns, bo = bias[o];
    float z = YZ[(size_t)p * N2 + O + o];
    int js[KNN];
    #pragma unroll
    for (int k = 0; k < KNN; ++k) js[k] = idx[(size_t)p * KNN + k];
    float m = -INFINITY;
    #pragma unroll
    for (int k = 0; k < KNN; ++k) {
        float y = YZ[(size_t)(bbase + js[k]) * N2 + o];
        m = fmaxf(m, leaky((y + z) * s + bo));
    }
    cat[(size_t)p * CSTR + outOff + o] = m;
}

// ---------------- fused W5 matmul + bn + leaky + partial max/sum pool over n ----------------
#define RSTAGE 16
__global__ __launch_bounds__(256) void pool_w5_kernel(const float* __restrict__ cat, const float* __restrict__ W5t,
                                                      const float* __restrict__ g5, const float* __restrict__ b5,
                                                      float* __restrict__ pmax, float* __restrict__ psum) {
    __shared__ float rows[RSTAGE][CSTR];   // 33.3 KB
    int blk = blockIdx.x;
    int nc = blk & 31; int rest = blk >> 5; int ot = rest & 3; int b = rest >> 2;
    int o = ot * 256 + threadIdx.x;
    const float bns = 1.0f / sqrtf(1.0f + 1e-5f);
    float s = g5[o] * bns, bo = b5[o];
    float vmax = -INFINITY, vsum = 0.f;
    for (int n0 = nc * 64; n0 < nc * 64 + 64; n0 += RSTAGE) {
        __syncthreads();
        for (int e = threadIdx.x; e < RSTAGE * (CSTR / 4); e += 256) {
            int r = e / (CSTR / 4), cg = e - r * (CSTR / 4);
            *reinterpret_cast<float4*>(&rows[r][4 * cg]) =
                *reinterpret_cast<const float4*>(&cat[((size_t)b * NP + n0 + r) * CSTR + 4 * cg]);
        }
        __syncthreads();
        float acc[RSTAGE];
        #pragma unroll
        for (int r = 0; r < RSTAGE; ++r) acc[r] = 0.f;
        for (int c = 0; c < CSTR; c += 4) {
            float w0 = W5t[(size_t)(c + 0) * 1024 + o];
            float w1 = W5t[(size_t)(c + 1) * 1024 + o];
            float w2 = W5t[(size_t)(c + 2) * 1024 + o];
            float w3 = W5t[(size_t)(c + 3) * 1024 + o];
            #pragma unroll
            for (int r = 0; r < RSTAGE; ++r) {
                float4 rv = *reinterpret_cast<const float4*>(&rows[r][c]);
                acc[r] += rv.x * w0 + rv.y * w1 + rv.z * w2 + rv.w * w3;
            }
        }
        #pragma unroll
        for (int r = 0; r < RSTAGE; ++r) {
            float v = leaky(acc[r] * s + bo);
            vmax = fmaxf(vmax, v); vsum += v;
        }
    }
    pmax[((size_t)b * 1024 + o) * 32 + nc] = vmax;
    psum[((size_t)b * 1024 + o) * 32 + nc] = vsum;
}

__global__ void pool_reduce_kernel(const float* __restrict__ pmax, const float* __restrict__ psum,
                                   float* __restrict__ f0) {
    int i = blockIdx.x * blockDim.x + threadIdx.x;
    if (i >= NB * 1024) return;
    int b = i >> 10, o = i & 1023;
    float m = -INFINITY, sm = 0.f;
    for (int nc = 0; nc < 32; ++nc) { m = fmaxf(m, pmax[(size_t)i * 32 + nc]); sm += psum[(size_t)i * 32 + nc]; }
    f0[(size_t)b * 2048 + o] = m;
    f0[(size_t)b * 2048 + 1024 + o] = sm * (1.0f / 2048.0f);
}

// ---------------- dense: one thread per (b, o) ----------------
__global__ void dense_kernel(const float* __restrict__ in, const float* __restrict__ W,
                             const float* __restrict__ bl, const float* __restrict__ g,
                             const float* __restrict__ bb, float* __restrict__ out,
                             int In, int Out, int act) {
    int i = blockIdx.x * blockDim.x + threadIdx.x;
    if (i >= NB * Out) return;
    int b = i / Out, o = i - b * Out;
    const float* w = W + (size_t)o * In;
    const float* xv = in + (size_t)b * In;
    float acc = 0.f;
    for (int c = 0; c < In; ++c) acc += xv[c] * w[c];
    acc += bl[o];
    if (act) {
        const float bns = 1.0f / sqrtf(1.0f + 1e-5f);
        acc = leaky(acc * (g[o] * bns) + bb[o]);
    }
    out[i] = acc;
}

extern "C" void kernel_launch(void* const* d_in, const int* in_sizes, int n_in,
                              void* d_out, int out_size, void* d_ws, size_t ws_size,
                              hipStream_t stream) {
    const float* x   = (const float*)d_in[0];
    const float* W1  = (const float*)d_in[2];
    const float* W2  = (const float*)d_in[3];
    const float* W3  = (const float*)d_in[4];
    const float* W4  = (const float*)d_in[5];
    const float* W5  = (const float*)d_in[6];
    const float* Wl1 = (const float*)d_in[7];
    const float* bl1 = (const float*)d_in[8];
    const float* Wl2 = (const float*)d_in[9];
    const float* bl2 = (const float*)d_in[10];
    const float* Wl3 = (const float*)d_in[11];
    const float* bl3 = (const float*)d_in[12];
    const float* g1 = (const float*)d_in[13]; const float* b1 = (const float*)d_in[14];
    const float* g2 = (const float*)d_in[15]; const float* b2 = (const float*)d_in[16];
    const float* g3 = (const float*)d_in[17]; const float* b3 = (const float*)d_in[18];
    const float* g4 = (const float*)d_in[19]; const float* b4 = (const float*)d_in[20];
    const float* g5 = (const float*)d_in[21]; const float* b5 = (const float*)d_in[22];
    const float* g6 = (const float*)d_in[23]; const float* bb6 = (const float*)d_in[24];
    const float* g7 = (const float*)d_in[25]; const float* bb7 = (const float*)d_in[26];

    float* ws = (float*)d_ws;
    size_t off = 0;
    float* CAT = ws + off; off += (size_t)NB * NP * CSTR;
    float* SQ  = ws + off; off += NB * NP;
    int*   IDX = (int*)(ws + off); off += (size_t)NB * NP * KNN;
    float* WYZ1 = ws + off; off += 4 * 128;
    float* WYZ2 = ws + off; off += 68 * 128;
    float* WYZ3 = ws + off; off += 132 * 256;
    float* WYZ4 = ws + off; off += 260 * 512;
    float* W5T = ws + off; off += 520 * 1024;
    float* YZ  = ws + off; off += (size_t)NB * NP * 512;   // 33.5 MB, reused per layer
    // pooling/head buffers alias YZ (temporally disjoint: YZ dead after last combine)
    float* PMAX = YZ;
    float* PSUM = PMAX + (size_t)NB * 1024 * 32;
    float* F0 = PSUM + (size_t)NB * 1024 * 32;
    float* F1 = F0 + NB * 2048;
    float* F2 = F1 + NB * 512;
    (void)off; (void)ws_size; (void)in_sizes; (void)n_in; (void)out_size;

    dim3 b256(256);
    const int M16 = NB * NP / 16;   // 1024 row-blocks

    tx_kernel<<<(NB * NP + 255) / 256, b256, 0, stream>>>(x, CAT);
    buildWyz<<<(4 * 128 + 255) / 256, b256, 0, stream>>>(W1, WYZ1, 64, 3, 4);
    buildWyz<<<(68 * 128 + 255) / 256, b256, 0, stream>>>(W2, WYZ2, 64, 67, 68);
    buildWyz<<<(132 * 256 + 255) / 256, b256, 0, stream>>>(W3, WYZ3, 128, 131, 132);
    buildWyz<<<(260 * 512 + 255) / 256, b256, 0, stream>>>(W4, WYZ4, 256, 259, 260);
    transposeW5<<<(520 * 1024 + 255) / 256, b256, 0, stream>>>(W5, W5T);

    // layer 1: knn on xc (C=4 @0); GEMM over cols [0,4) -> N2=128; combine -> col 4
    sqnorm_kernel<<<(NB * NP + 255) / 256, b256, 0, stream>>>(CAT, 0, 4, SQ);
    knn2_kernel<4><<<NB * NP / 4, b256, 0, stream>>>(CAT, 0, SQ, IDX);
    gemm_yz_kernel<4, 128><<<dim3(M16, 1), 128, 0, stream>>>(CAT, 0, WYZ1, 128, YZ);
    combine_kernel<64><<<NB * NP / 4, b256, 0, stream>>>(YZ, 128, IDX, g1, b1, CAT, 4);
    // layer 2: knn on x1 (C=64 @4); GEMM over cols [0,68); combine -> col 68
    sqnorm_kernel<<<(NB * NP + 255) / 256, b256, 0, stream>>>(CAT, 4, 64, SQ);
    knn2_kernel<64><<<NB * NP / 4, b256, 0, stream>>>(CAT, 4, SQ, IDX);
    gemm_yz_kernel<68, 128><<<dim3(M16, 1), 128, 0, stream>>>(CAT, 0, WYZ2, 128, YZ);
    combine_kernel<64><<<NB * NP / 4, b256, 0, stream>>>(YZ, 128, IDX, g2, b2, CAT, 68);
    // layer 3: knn on x2 (C=64 @68); GEMM over cols [0,132); combine -> col 132
    sqnorm_kernel<<<(NB * NP + 255) / 256, b256, 0, stream>>>(CAT, 68, 64, SQ);
    knn2_kernel<64><<<NB * NP / 4, b256, 0, stream>>>(CAT, 68, SQ, IDX);
    gemm_yz_kernel<132, 256><<<dim3(M16, 1), 256, 0, stream>>>(CAT, 0, WYZ3, 256, YZ);
    combine_kernel<128><<<NB * NP / 2, b256, 0, stream>>>(YZ, 256, IDX, g3, b3, CAT, 132);
    // layer 4: knn on x3 (C=128 @132); GEMM over cols [0,260); combine -> col 260
    sqnorm_kernel<<<(NB * NP + 255) / 256, b256, 0, stream>>>(CAT, 132, 128, SQ);
    knn2_kernel<128><<<NB * NP / 4, b256, 0, stream>>>(CAT, 132, SQ, IDX);
    gemm_yz_kernel<260, 256><<<dim3(M16, 2), 256, 0, stream>>>(CAT, 0, WYZ4, 512, YZ);
    combine_kernel<256><<<NB * NP, b256, 0, stream>>>(YZ, 512, IDX, g4, b4, CAT, 260);

    // W5 + bn + leaky + global max/mean pool
    pool_w5_kernel<<<NB * 4 * 32, b256, 0, stream>>>(CAT, W5T, g5, b5, PMAX, PSUM);
    pool_reduce_kernel<<<(NB * 1024 + 255) / 256, b256, 0, stream>>>(PMAX, PSUM, F0);

    // MLP head
    dense_kernel<<<(NB * 512 + 255) / 256, b256, 0, stream>>>(F0, Wl1, bl1, g6, bb6, F1, 2048, 512, 1);
    dense_kernel<<<(NB * 256 + 255) / 256, b256, 0, stream>>>(F1, Wl2, bl2, g7, bb7, F2, 512, 256, 1);
    dense_kernel<<<(NB * 40 + 255) / 256, b256, 0, stream>>>(F2, Wl3, bl3, nullptr, nullptr,
                                                             (float*)d_out, 256, 40, 0);
}

// Round 7
// 1876.674 us; speedup vs baseline: 17.1167x; 17.1167x over previous
//
#include <hip/hip_runtime.h>
#include <math.h>

#define NB 8
#define NP 2048
#define KNN 20
#define CSTR 520          // padded row stride of the cat feature buffer (floats)
#define NEG 0.2f
// padded column layout: [x:0..3)[pad:3][x1:4..68)[x2:68..132)[x3:132..260)[x4:260..516)
// every slice start is a multiple of 4 floats (16B-aligned)

__device__ __forceinline__ float leaky(float x) { return x >= 0.0f ? x : NEG * x; }

// ---------------- transpose x (B,3,N) -> cat[:, :, 0:3], zero pad col 3 ----------------
__global__ void tx_kernel(const float* __restrict__ x, float* __restrict__ cat) {
    int i = blockIdx.x * blockDim.x + threadIdx.x;
    if (i >= NB * NP) return;
    int b = i / NP, n = i % NP;
    float* r = cat + (size_t)i * CSTR;
    r[0] = x[((size_t)b * 3 + 0) * NP + n];
    r[1] = x[((size_t)b * 3 + 1) * NP + n];
    r[2] = x[((size_t)b * 3 + 2) * NP + n];
    r[3] = 0.0f;
    r[516] = 0.f; r[517] = 0.f; r[518] = 0.f; r[519] = 0.f;
}

// ---------------- conv weights W (O, 2*Cin) -> Wyz (PC, 2*O): [Wd | Wc - Wd] ----------------
__global__ void buildWyz(const float* __restrict__ W, float* __restrict__ Wyz,
                         int O, int Cin, int PC) {
    int i = blockIdx.x * blockDim.x + threadIdx.x;
    int N2 = 2 * O;
    if (i >= PC * N2) return;
    int q = i / N2, n = i - q * N2;
    float v = 0.0f;
    if (q != 3) {
        int c = (q < 3) ? q : q - 1;
        if (c < Cin) {
            int o = (n < O) ? n : n - O;
            float wd = W[(size_t)o * (2 * Cin) + c];
            v = (n < O) ? wd : (W[(size_t)o * (2 * Cin) + Cin + c] - wd);
        }
    }
    Wyz[i] = v;
}

// ---------------- W5 (1024, 515) -> padded transposed W5t (520, 1024) ----------------
__global__ void transposeW5(const float* __restrict__ W, float* __restrict__ Wt) {
    int i = blockIdx.x * blockDim.x + threadIdx.x;
    if (i >= 520 * 1024) return;
    int p = i >> 10, o = i & 1023;
    float v = 0.0f;
    if (p < 516 && p != 3) {
        int c = (p < 3) ? p : p - 1;
        v = W[(size_t)o * 515 + c];
    }
    Wt[i] = v;
}

// ---------------- squared norms of feature slice (padded C, pad col is zero) ----------------
__global__ void sqnorm_kernel(const float* __restrict__ cat, int off, int C, float* __restrict__ sq) {
    int i = blockIdx.x * blockDim.x + threadIdx.x;
    if (i >= NB * NP) return;
    const float* f = cat + (size_t)i * CSTR + off;
    float s = 0.f;
    for (int c = 0; c < C; c += 4) {
        float4 v = *reinterpret_cast<const float4*>(f + c);
        s += v.x * v.x + v.y * v.y + v.z * v.z + v.w * v.w;
    }
    sq[i] = s;
}

// ---------------- XT: slice transpose cat[b][n][off+c] -> XT[bl][c][n] ----------------
template <int K>
__global__ __launch_bounds__(256) void xt_kernel(const float* __restrict__ cat, int off,
                                                 float* __restrict__ XT, int b0) {
    __shared__ float lds[64][K + 1];     // +1 pad -> conflict-free column reads
    int bl = blockIdx.x;                 // group-local batch
    int b = b0 + bl;
    int n0 = blockIdx.y * 64;
    const float* src = cat + ((size_t)(b * NP + n0)) * CSTR + off;
    for (int e = threadIdx.x; e < 64 * (K / 4); e += 256) {
        int r = e / (K / 4), cg = e - r * (K / 4);
        float4 v = *reinterpret_cast<const float4*>(src + (size_t)r * CSTR + 4 * cg);
        lds[r][4 * cg + 0] = v.x; lds[r][4 * cg + 1] = v.y;
        lds[r][4 * cg + 2] = v.z; lds[r][4 * cg + 3] = v.w;
    }
    __syncthreads();
    float* dst = XT + (size_t)bl * K * NP;
    for (int e = threadIdx.x; e < 64 * K; e += 256) {
        int c = e >> 6, tn = e & 63;
        dst[(size_t)c * NP + n0 + tn] = lds[tn][c];
    }
}

// ---------------- distance GEMM: D[row][col] = 2*dot(X[row],X[col]) - sq_r - sq_c ----------------
// 16-row register blocking (proven pool_w5 pattern, 36 VGPR, no spill).
template <int K>
__global__ __launch_bounds__(256) void distgemm_kernel(const float* __restrict__ cat, int off,
                                                       const float* __restrict__ sq,
                                                       const float* __restrict__ XT,
                                                       float* __restrict__ D, int b0) {
    __shared__ float rows[16][K];
    int rb = blockIdx.x;
    int bl = rb / (NP / 16);             // group-local batch
    int b = b0 + bl;
    int nb = (rb % (NP / 16)) * 16;
    int col = blockIdx.y * 256 + threadIdx.x;
    const float* src = cat + ((size_t)(b * NP + nb)) * CSTR + off;
    for (int e = threadIdx.x; e < 16 * (K / 4); e += 256) {
        int r = e / (K / 4), cg = e - r * (K / 4);
        *reinterpret_cast<float4*>(&rows[r][4 * cg]) =
            *reinterpret_cast<const float4*>(src + (size_t)r * CSTR + 4 * cg);
    }
    __syncthreads();
    const float* Wp = XT + (size_t)bl * K * NP;
    float acc[16];
    #pragma unroll
    for (int r = 0; r < 16; ++r) acc[r] = 0.f;
    for (int c = 0; c < K; c += 4) {
        float w0 = Wp[(size_t)(c + 0) * NP + col];
        float w1 = Wp[(size_t)(c + 1) * NP + col];
        float w2 = Wp[(size_t)(c + 2) * NP + col];
        float w3 = Wp[(size_t)(c + 3) * NP + col];
        #pragma unroll
        for (int r = 0; r < 16; ++r) {
            float4 rv = *reinterpret_cast<const float4*>(&rows[r][c]);
            acc[r] += rv.x * w0 + rv.y * w1 + rv.z * w2 + rv.w * w3;
        }
    }
    float sqc = sq[(size_t)b * NP + col];
    float* drow = D + ((size_t)rb * 16) * NP + col;
    #pragma unroll
    for (int r = 0; r < 16; ++r) {
        float sqr = sq[(size_t)b * NP + nb + r];
        drow[(size_t)r * NP] = 2.f * acc[r] - sqr - sqc;
    }
}

// ---------------- top-k selection only: 4 queries/block, lane-strided LDS, NO barriers ----------------
__global__ __launch_bounds__(256) void topk_kernel(const float* __restrict__ D,
                                                   int* __restrict__ idxout, int b0) {
    __shared__ float distL[4][NP];       // 32 KB -> 5 blocks/CU
    int wave = threadIdx.x >> 6, lane = threadIdx.x & 63;
    int ql = blockIdx.x * 4 + wave;      // group-local query row
    const float* drow = D + (size_t)ql * NP;
    #pragma unroll
    for (int t = 0; t < 32; ++t)
        distL[wave][t * 64 + lane] = drow[t * 64 + lane];
    size_t q = (size_t)b0 * NP + ql;     // global row for IDX
    for (int k = 0; k < KNN; ++k) {
        float bv = -INFINITY; int bj = 0x7fffffff;
        #pragma unroll
        for (int t = 0; t < 32; ++t) {
            float v = distL[wave][t * 64 + lane];
            if (v > bv) { bv = v; bj = t * 64 + lane; }   // ascending j; strict > keeps lowest
        }
        for (int s = 32; s; s >>= 1) {
            float ov = __shfl_xor(bv, s);
            int oj = __shfl_xor(bj, s);
            if (ov > bv || (ov == bv && oj < bj)) { bv = ov; bj = oj; }
        }
        if (lane == 0) idxout[q * KNN + k] = bj;
        if ((bj & 63) == lane) distL[wave][bj] = -INFINITY;  // owner is sole reader
    }
}

// ---------------- YZ GEMM: YZ[p][:] = cat[p][0:K] @ Wyz (K x N2) ----------------
template <int K, int NT>
__global__ __launch_bounds__(NT) void gemm_yz_kernel(const float* __restrict__ cat, int off,
                                                     const float* __restrict__ W, int N2,
                                                     float* __restrict__ YZ) {
    __shared__ float rows[16][K];
    int col = blockIdx.y * NT + threadIdx.x;
    const float* src = cat + (size_t)blockIdx.x * 16 * CSTR + off;
    for (int e = threadIdx.x; e < 16 * (K / 4); e += NT) {
        int r = e / (K / 4), cg = e - r * (K / 4);
        *reinterpret_cast<float4*>(&rows[r][4 * cg]) =
            *reinterpret_cast<const float4*>(src + (size_t)r * CSTR + 4 * cg);
    }
    __syncthreads();
    float acc[16];
    #pragma unroll
    for (int r = 0; r < 16; ++r) acc[r] = 0.f;
    for (int c = 0; c < K; c += 4) {
        float w0 = W[(size_t)(c + 0) * N2 + col];
        float w1 = W[(size_t)(c + 1) * N2 + col];
        float w2 = W[(size_t)(c + 2) * N2 + col];
        float w3 = W[(size_t)(c + 3) * N2 + col];
        #pragma unroll
        for (int r = 0; r < 16; ++r) {
            float4 rv = *reinterpret_cast<const float4*>(&rows[r][c]);
            acc[r] += rv.x * w0 + rv.y * w1 + rv.z * w2 + rv.w * w3;
        }
    }
    float* dst = YZ + (size_t)blockIdx.x * 16 * N2 + col;
    #pragma unroll
    for (int r = 0; r < 16; ++r) dst[(size_t)r * N2] = acc[r];
}

// ---------------- combine: out[p][o] = max_k leaky((Y[j_k][o] + Z[p][o])*s + b) ----------------
template <int O>
__global__ __launch_bounds__(256) void combine_kernel(const float* __restrict__ YZ, int N2,
                                                      const int* __restrict__ idx,
                                                      const float* __restrict__ g,
                                                      const float* __restrict__ bias,
                                                      float* __restrict__ cat, int outOff) {
    constexpr int PPB = 256 / O;
    int sub = threadIdx.x / O, o = threadIdx.x % O;
    int p = blockIdx.x * PPB + sub;
    int bbase = p & ~(NP - 1);             // batch-global row base for local neighbor ids
    const float bns = 1.0f / sqrtf(1.0f + 1e-5f);
    float s = g[o] * bns, bo = bias[o];
    float z = YZ[(size_t)p * N2 + O + o];
    int js[KNN];
    #pragma unroll
    for (int k = 0; k < KNN; ++k) js[k] = idx[(size_t)p * KNN + k];
    float m = -INFINITY;
    #pragma unroll
    for (int k = 0; k < KNN; ++k) {
        float y = YZ[(size_t)(bbase + js[k]) * N2 + o];
        m = fmaxf(m, leaky((y + z) * s + bo));
    }
    cat[(size_t)p * CSTR + outOff + o] = m;
}

// ---------------- fused W5 matmul + bn + leaky + partial max/sum pool over n ----------------
#define RSTAGE 16
__global__ __launch_bounds__(256) void pool_w5_kernel(const float* __restrict__ cat, const float* __restrict__ W5t,
                                                      const float* __restrict__ g5, const float* __restrict__ b5,
                                                      float* __restrict__ pmax, float* __restrict__ psum) {
    __shared__ float rows[RSTAGE][CSTR];   // 33.3 KB
    int blk = blockIdx.x;
    int nc = blk & 31; int rest = blk >> 5; int ot = rest & 3; int b = rest >> 2;
    int o = ot * 256 + threadIdx.x;
    const float bns = 1.0f / sqrtf(1.0f + 1e-5f);
    float s = g5[o] * bns, bo = b5[o];
    float vmax = -INFINITY, vsum = 0.f;
    for (int n0 = nc * 64; n0 < nc * 64 + 64; n0 += RSTAGE) {
        __syncthreads();
        for (int e = threadIdx.x; e < RSTAGE * (CSTR / 4); e += 256) {
            int r = e / (CSTR / 4), cg = e - r * (CSTR / 4);
            *reinterpret_cast<float4*>(&rows[r][4 * cg]) =
                *reinterpret_cast<const float4*>(&cat[((size_t)b * NP + n0 + r) * CSTR + 4 * cg]);
        }
        __syncthreads();
        float acc[RSTAGE];
        #pragma unroll
        for (int r = 0; r < RSTAGE; ++r) acc[r] = 0.f;
        for (int c = 0; c < CSTR; c += 4) {
            float w0 = W5t[(size_t)(c + 0) * 1024 + o];
            float w1 = W5t[(size_t)(c + 1) * 1024 + o];
            float w2 = W5t[(size_t)(c + 2) * 1024 + o];
            float w3 = W5t[(size_t)(c + 3) * 1024 + o];
            #pragma unroll
            for (int r = 0; r < RSTAGE; ++r) {
                float4 rv = *reinterpret_cast<const float4*>(&rows[r][c]);
                acc[r] += rv.x * w0 + rv.y * w1 + rv.z * w2 + rv.w * w3;
            }
        }
        #pragma unroll
        for (int r = 0; r < RSTAGE; ++r) {
            float v = leaky(acc[r] * s + bo);
            vmax = fmaxf(vmax, v); vsum += v;
        }
    }
    pmax[((size_t)b * 1024 + o) * 32 + nc] = vmax;
    psum[((size_t)b * 1024 + o) * 32 + nc] = vsum;
}

__global__ void pool_reduce_kernel(const float* __restrict__ pmax, const float* __restrict__ psum,
                                   float* __restrict__ f0) {
    int i = blockIdx.x * blockDim.x + threadIdx.x;
    if (i >= NB * 1024) return;
    int b = i >> 10, o = i & 1023;
    float m = -INFINITY, sm = 0.f;
    for (int nc = 0; nc < 32; ++nc) { m = fmaxf(m, pmax[(size_t)i * 32 + nc]); sm += psum[(size_t)i * 32 + nc]; }
    f0[(size_t)b * 2048 + o] = m;
    f0[(size_t)b * 2048 + 1024 + o] = sm * (1.0f / 2048.0f);
}

// ---------------- dense: one thread per (b, o) ----------------
__global__ void dense_kernel(const float* __restrict__ in, const float* __restrict__ W,
                             const float* __restrict__ bl, const float* __restrict__ g,
                             const float* __restrict__ bb, float* __restrict__ out,
                             int In, int Out, int act) {
    int i = blockIdx.x * blockDim.x + threadIdx.x;
    if (i >= NB * Out) return;
    int b = i / Out, o = i - b * Out;
    const float* w = W + (size_t)o * In;
    const float* xv = in + (size_t)b * In;
    float acc = 0.f;
    for (int c = 0; c < In; ++c) acc += xv[c] * w[c];
    acc += bl[o];
    if (act) {
        const float bns = 1.0f / sqrtf(1.0f + 1e-5f);
        acc = leaky(acc * (g[o] * bns) + bb[o]);
    }
    out[i] = acc;
}

extern "C" void kernel_launch(void* const* d_in, const int* in_sizes, int n_in,
                              void* d_out, int out_size, void* d_ws, size_t ws_size,
                              hipStream_t stream) {
    const float* x   = (const float*)d_in[0];
    const float* W1  = (const float*)d_in[2];
    const float* W2  = (const float*)d_in[3];
    const float* W3  = (const float*)d_in[4];
    const float* W4  = (const float*)d_in[5];
    const float* W5  = (const float*)d_in[6];
    const float* Wl1 = (const float*)d_in[7];
    const float* bl1 = (const float*)d_in[8];
    const float* Wl2 = (const float*)d_in[9];
    const float* bl2 = (const float*)d_in[10];
    const float* Wl3 = (const float*)d_in[11];
    const float* bl3 = (const float*)d_in[12];
    const float* g1 = (const float*)d_in[13]; const float* b1 = (const float*)d_in[14];
    const float* g2 = (const float*)d_in[15]; const float* b2 = (const float*)d_in[16];
    const float* g3 = (const float*)d_in[17]; const float* b3 = (const float*)d_in[18];
    const float* g4 = (const float*)d_in[19]; const float* b4 = (const float*)d_in[20];
    const float* g5 = (const float*)d_in[21]; const float* b5 = (const float*)d_in[22];
    const float* g6 = (const float*)d_in[23]; const float* bb6 = (const float*)d_in[24];
    const float* g7 = (const float*)d_in[25]; const float* bb7 = (const float*)d_in[26];

    float* ws = (float*)d_ws;
    size_t off = 0;
    float* CAT = ws + off; off += (size_t)NB * NP * CSTR;
    float* SQ  = ws + off; off += NB * NP;
    int*   IDX = (int*)(ws + off); off += (size_t)NB * NP * KNN;
    float* WYZ1 = ws + off; off += 4 * 128;
    float* WYZ2 = ws + off; off += 68 * 128;
    float* WYZ3 = ws + off; off += 132 * 256;
    float* WYZ4 = ws + off; off += 260 * 512;
    float* W5T = ws + off; off += 520 * 1024;
    float* BIG = ws + off;                    // shared region: DMAT+XT | YZ | pool buffers
    size_t wsfl = ws_size / 4;
    size_t avail = (wsfl > off) ? (wsfl - off) : 0;
    const size_t yzneed = (size_t)NB * NP * 512;
    int G = 1;
    for (int g = 8; g >= 1; g >>= 1) {
        size_t need = (size_t)g * NP * 2048 + (size_t)g * 128 * NP;   // DMAT + XT(K<=128)
        size_t big = (need > yzneed) ? need : yzneed;
        if (big <= avail) { G = g; break; }
    }
    float* DMAT = BIG;
    float* XT   = BIG + (size_t)G * NP * 2048;
    float* YZ   = BIG;
    float* PMAX = BIG;
    float* PSUM = PMAX + (size_t)NB * 1024 * 32;
    float* F0 = PSUM + (size_t)NB * 1024 * 32;
    float* F1 = F0 + NB * 2048;
    float* F2 = F1 + NB * 512;
    (void)in_sizes; (void)n_in; (void)out_size;

    dim3 b256(256);
    const int M16 = NB * NP / 16;   // 1024 row-blocks

    tx_kernel<<<(NB * NP + 255) / 256, b256, 0, stream>>>(x, CAT);
    buildWyz<<<(4 * 128 + 255) / 256, b256, 0, stream>>>(W1, WYZ1, 64, 3, 4);
    buildWyz<<<(68 * 128 + 255) / 256, b256, 0, stream>>>(W2, WYZ2, 64, 67, 68);
    buildWyz<<<(132 * 256 + 255) / 256, b256, 0, stream>>>(W3, WYZ3, 128, 131, 132);
    buildWyz<<<(260 * 512 + 255) / 256, b256, 0, stream>>>(W4, WYZ4, 256, 259, 260);
    transposeW5<<<(520 * 1024 + 255) / 256, b256, 0, stream>>>(W5, W5T);

    // macro-ish per-layer KNN: sqnorm -> (xt, distgemm, topk) per batch group
#define RUN_KNN(KK, OFFC)                                                                   \
    do {                                                                                    \
        sqnorm_kernel<<<(NB * NP + 255) / 256, b256, 0, stream>>>(CAT, OFFC, KK, SQ);       \
        for (int b0 = 0; b0 < NB; b0 += G) {                                                \
            xt_kernel<KK><<<dim3(G, NP / 64), b256, 0, stream>>>(CAT, OFFC, XT, b0);        \
            distgemm_kernel<KK><<<dim3(G * (NP / 16), 8), b256, 0, stream>>>(               \
                CAT, OFFC, SQ, XT, DMAT, b0);                                               \
            topk_kernel<<<G * NP / 4, b256, 0, stream>>>(DMAT, IDX, b0);                    \
        }                                                                                   \
    } while (0)

    // layer 1: knn on xc (C=4 @0); GEMM over cols [0,4) -> N2=128; combine -> col 4
    RUN_KNN(4, 0);
    gemm_yz_kernel<4, 128><<<dim3(M16, 1), 128, 0, stream>>>(CAT, 0, WYZ1, 128, YZ);
    combine_kernel<64><<<NB * NP / 4, b256, 0, stream>>>(YZ, 128, IDX, g1, b1, CAT, 4);
    // layer 2: knn on x1 (C=64 @4); GEMM over cols [0,68); combine -> col 68
    RUN_KNN(64, 4);
    gemm_yz_kernel<68, 128><<<dim3(M16, 1), 128, 0, stream>>>(CAT, 0, WYZ2, 128, YZ);
    combine_kernel<64><<<NB * NP / 4, b256, 0, stream>>>(YZ, 128, IDX, g2, b2, CAT, 68);
    // layer 3: knn on x2 (C=64 @68); GEMM over cols [0,132); combine -> col 132
    RUN_KNN(64, 68);
    gemm_yz_kernel<132, 256><<<dim3(M16, 1), 256, 0, stream>>>(CAT, 0, WYZ3, 256, YZ);
    combine_kernel<128><<<NB * NP / 2, b256, 0, stream>>>(YZ, 256, IDX, g3, b3, CAT, 132);
    // layer 4: knn on x3 (C=128 @132); GEMM over cols [0,260); combine -> col 260
    RUN_KNN(128, 132);
    gemm_yz_kernel<260, 256><<<dim3(M16, 2), 256, 0, stream>>>(CAT, 0, WYZ4, 512, YZ);
    combine_kernel<256><<<NB * NP, b256, 0, stream>>>(YZ, 512, IDX, g4, b4, CAT, 260);
#undef RUN_KNN

    // W5 + bn + leaky + global max/mean pool
    pool_w5_kernel<<<NB * 4 * 32, b256, 0, stream>>>(CAT, W5T, g5, b5, PMAX, PSUM);
    pool_reduce_kernel<<<(NB * 1024 + 255) / 256, b256, 0, stream>>>(PMAX, PSUM, F0);

    // MLP head
    dense_kernel<<<(NB * 512 + 255) / 256, b256, 0, stream>>>(F0, Wl1, bl1, g6, bb6, F1, 2048, 512, 1);
    dense_kernel<<<(NB * 256 + 255) / 256, b256, 0, stream>>>(F1, Wl2, bl2, g7, bb7, F2, 512, 256, 1);
    dense_kernel<<<(NB * 40 + 255) / 256, b256, 0, stream>>>(F2, Wl3, bl3, nullptr, nullptr,
                                                             (float*)d_out, 256, 40, 0);
}

// Round 8
// 1645.140 us; speedup vs baseline: 19.5257x; 1.1407x over previous
//
#include <hip/hip_runtime.h>
#include <math.h>

#define NB 8
#define NP 2048
#define KNN 20
#define CSTR 520          // padded row stride of the cat feature buffer (floats)
#define NEG 0.2f
// padded column layout: [x:0..3)[pad:3][x1:4..68)[x2:68..132)[x3:132..260)[x4:260..516)
// every slice start is a multiple of 4 floats (16B-aligned)

__device__ __forceinline__ float leaky(float x) { return x >= 0.0f ? x : NEG * x; }

// ---------------- transpose x (B,3,N) -> cat[:, :, 0:3], zero pad col 3 ----------------
__global__ void tx_kernel(const float* __restrict__ x, float* __restrict__ cat) {
    int i = blockIdx.x * blockDim.x + threadIdx.x;
    if (i >= NB * NP) return;
    int b = i / NP, n = i % NP;
    float* r = cat + (size_t)i * CSTR;
    r[0] = x[((size_t)b * 3 + 0) * NP + n];
    r[1] = x[((size_t)b * 3 + 1) * NP + n];
    r[2] = x[((size_t)b * 3 + 2) * NP + n];
    r[3] = 0.0f;
    r[516] = 0.f; r[517] = 0.f; r[518] = 0.f; r[519] = 0.f;
}

// ---------------- conv weights W (O, 2*Cin) -> Wyz (PC, 2*O): [Wd | Wc - Wd] ----------------
__global__ void buildWyz(const float* __restrict__ W, float* __restrict__ Wyz,
                         int O, int Cin, int PC) {
    int i = blockIdx.x * blockDim.x + threadIdx.x;
    int N2 = 2 * O;
    if (i >= PC * N2) return;
    int q = i / N2, n = i - q * N2;
    float v = 0.0f;
    if (q != 3) {
        int c = (q < 3) ? q : q - 1;
        if (c < Cin) {
            int o = (n < O) ? n : n - O;
            float wd = W[(size_t)o * (2 * Cin) + c];
            v = (n < O) ? wd : (W[(size_t)o * (2 * Cin) + Cin + c] - wd);
        }
    }
    Wyz[i] = v;
}

// ---------------- W5 (1024, 515) -> padded transposed W5t (520, 1024) ----------------
__global__ void transposeW5(const float* __restrict__ W, float* __restrict__ Wt) {
    int i = blockIdx.x * blockDim.x + threadIdx.x;
    if (i >= 520 * 1024) return;
    int p = i >> 10, o = i & 1023;
    float v = 0.0f;
    if (p < 516 && p != 3) {
        int c = (p < 3) ? p : p - 1;
        v = W[(size_t)o * 515 + c];
    }
    Wt[i] = v;
}

// ---------------- squared norms of feature slice (padded C, pad col is zero) ----------------
__global__ void sqnorm_kernel(const float* __restrict__ cat, int off, int C, float* __restrict__ sq) {
    int i = blockIdx.x * blockDim.x + threadIdx.x;
    if (i >= NB * NP) return;
    const float* f = cat + (size_t)i * CSTR + off;
    float s = 0.f;
    for (int c = 0; c < C; c += 4) {
        float4 v = *reinterpret_cast<const float4*>(f + c);
        s += v.x * v.x + v.y * v.y + v.z * v.z + v.w * v.w;
    }
    sq[i] = s;
}

// ---------------- XT: slice transpose cat[b][n][off+c] -> XT[bl][c][n] ----------------
template <int K>
__global__ __launch_bounds__(256) void xt_kernel(const float* __restrict__ cat, int off,
                                                 float* __restrict__ XT, int b0) {
    __shared__ float lds[64][K + 1];     // +1 pad -> conflict-free column reads
    int bl = blockIdx.x;                 // group-local batch
    int b = b0 + bl;
    int n0 = blockIdx.y * 64;
    const float* src = cat + ((size_t)(b * NP + n0)) * CSTR + off;
    for (int e = threadIdx.x; e < 64 * (K / 4); e += 256) {
        int r = e / (K / 4), cg = e - r * (K / 4);
        float4 v = *reinterpret_cast<const float4*>(src + (size_t)r * CSTR + 4 * cg);
        lds[r][4 * cg + 0] = v.x; lds[r][4 * cg + 1] = v.y;
        lds[r][4 * cg + 2] = v.z; lds[r][4 * cg + 3] = v.w;
    }
    __syncthreads();
    float* dst = XT + (size_t)bl * K * NP;
    for (int e = threadIdx.x; e < 64 * K; e += 256) {
        int c = e >> 6, tn = e & 63;
        dst[(size_t)c * NP + n0 + tn] = lds[tn][c];
    }
}

// ---------------- distance GEMM: D[row][col] = 2*dot(X[row],X[col]) - sq_r - sq_c ----------------
// 16-row x 2-col register blocking: float2 XT loads, 128 FMAs per c-group.
template <int K>
__global__ __launch_bounds__(256) void distgemm_kernel(const float* __restrict__ cat, int off,
                                                       const float* __restrict__ sq,
                                                       const float* __restrict__ XT,
                                                       float* __restrict__ D, int b0) {
    __shared__ float rows[16][K];
    int rb = blockIdx.x;
    int bl = rb / (NP / 16);             // group-local batch
    int b = b0 + bl;
    int nb = (rb % (NP / 16)) * 16;
    int col = blockIdx.y * 512 + threadIdx.x * 2;
    const float* src = cat + ((size_t)(b * NP + nb)) * CSTR + off;
    for (int e = threadIdx.x; e < 16 * (K / 4); e += 256) {
        int r = e / (K / 4), cg = e - r * (K / 4);
        *reinterpret_cast<float4*>(&rows[r][4 * cg]) =
            *reinterpret_cast<const float4*>(src + (size_t)r * CSTR + 4 * cg);
    }
    __syncthreads();
    const float* Wp = XT + (size_t)bl * K * NP;
    float acc[2][16];
    #pragma unroll
    for (int r = 0; r < 16; ++r) { acc[0][r] = 0.f; acc[1][r] = 0.f; }
    for (int c = 0; c < K; c += 4) {
        float2 w0 = *reinterpret_cast<const float2*>(&Wp[(size_t)(c + 0) * NP + col]);
        float2 w1 = *reinterpret_cast<const float2*>(&Wp[(size_t)(c + 1) * NP + col]);
        float2 w2 = *reinterpret_cast<const float2*>(&Wp[(size_t)(c + 2) * NP + col]);
        float2 w3 = *reinterpret_cast<const float2*>(&Wp[(size_t)(c + 3) * NP + col]);
        #pragma unroll
        for (int r = 0; r < 16; ++r) {
            float4 rv = *reinterpret_cast<const float4*>(&rows[r][c]);
            acc[0][r] += rv.x * w0.x + rv.y * w1.x + rv.z * w2.x + rv.w * w3.x;
            acc[1][r] += rv.x * w0.y + rv.y * w1.y + rv.z * w2.y + rv.w * w3.y;
        }
    }
    float sqc0 = sq[(size_t)b * NP + col];
    float sqc1 = sq[(size_t)b * NP + col + 1];
    float* drow = D + ((size_t)rb * 16) * NP + col;
    #pragma unroll
    for (int r = 0; r < 16; ++r) {
        float sqr = sq[(size_t)b * NP + nb + r];
        float2 outv = make_float2(2.f * acc[0][r] - sqr - sqc0, 2.f * acc[1][r] - sqr - sqc1);
        *reinterpret_cast<float2*>(&drow[(size_t)r * NP]) = outv;
    }
}

// ---------------- top-k selection only: 4 queries/block, lane-strided LDS, NO barriers ----------------
__global__ __launch_bounds__(256) void topk_kernel(const float* __restrict__ D,
                                                   int* __restrict__ idxout, int b0) {
    __shared__ float distL[4][NP];       // 32 KB -> 5 blocks/CU
    int wave = threadIdx.x >> 6, lane = threadIdx.x & 63;
    int ql = blockIdx.x * 4 + wave;      // group-local query row
    const float* drow = D + (size_t)ql * NP;
    #pragma unroll
    for (int t = 0; t < 32; ++t)
        distL[wave][t * 64 + lane] = drow[t * 64 + lane];
    size_t q = (size_t)b0 * NP + ql;     // global row for IDX
    for (int k = 0; k < KNN; ++k) {
        float bv = -INFINITY; int bj = 0x7fffffff;
        #pragma unroll
        for (int t = 0; t < 32; ++t) {
            float v = distL[wave][t * 64 + lane];
            if (v > bv) { bv = v; bj = t * 64 + lane; }   // ascending j; strict > keeps lowest
        }
        for (int s = 32; s; s >>= 1) {
            float ov = __shfl_xor(bv, s);
            int oj = __shfl_xor(bj, s);
            if (ov > bv || (ov == bv && oj < bj)) { bv = ov; bj = oj; }
        }
        if (lane == 0) idxout[q * KNN + k] = bj;
        if ((bj & 63) == lane) distL[wave][bj] = -INFINITY;  // owner is sole reader
    }
}

// ---------------- YZ GEMM: YZ[p][:] = cat[p][0:K] @ Wyz (K x N2) ----------------
template <int K, int NT>
__global__ __launch_bounds__(NT) void gemm_yz_kernel(const float* __restrict__ cat, int off,
                                                     const float* __restrict__ W, int N2,
                                                     float* __restrict__ YZ) {
    __shared__ float rows[16][K];
    int col = blockIdx.y * NT + threadIdx.x;
    const float* src = cat + (size_t)blockIdx.x * 16 * CSTR + off;
    for (int e = threadIdx.x; e < 16 * (K / 4); e += NT) {
        int r = e / (K / 4), cg = e - r * (K / 4);
        *reinterpret_cast<float4*>(&rows[r][4 * cg]) =
            *reinterpret_cast<const float4*>(src + (size_t)r * CSTR + 4 * cg);
    }
    __syncthreads();
    float acc[16];
    #pragma unroll
    for (int r = 0; r < 16; ++r) acc[r] = 0.f;
    for (int c = 0; c < K; c += 4) {
        float w0 = W[(size_t)(c + 0) * N2 + col];
        float w1 = W[(size_t)(c + 1) * N2 + col];
        float w2 = W[(size_t)(c + 2) * N2 + col];
        float w3 = W[(size_t)(c + 3) * N2 + col];
        #pragma unroll
        for (int r = 0; r < 16; ++r) {
            float4 rv = *reinterpret_cast<const float4*>(&rows[r][c]);
            acc[r] += rv.x * w0 + rv.y * w1 + rv.z * w2 + rv.w * w3;
        }
    }
    float* dst = YZ + (size_t)blockIdx.x * 16 * N2 + col;
    #pragma unroll
    for (int r = 0; r < 16; ++r) dst[(size_t)r * N2] = acc[r];
}

// ---------------- combine: out[p][o] = max_k leaky((Y[j_k][o] + Z[p][o])*s + b) ----------------
template <int O>
__global__ __launch_bounds__(256) void combine_kernel(const float* __restrict__ YZ, int N2,
                                                      const int* __restrict__ idx,
                                                      const float* __restrict__ g,
                                                      const float* __restrict__ bias,
                                                      float* __restrict__ cat, int outOff) {
    constexpr int PPB = 256 / O;
    int sub = threadIdx.x / O, o = threadIdx.x % O;
    int p = blockIdx.x * PPB + sub;
    int bbase = p & ~(NP - 1);             // batch-global row base for local neighbor ids
    const float bns = 1.0f / sqrtf(1.0f + 1e-5f);
    float s = g[o] * bns, bo = bias[o];
    float z = YZ[(size_t)p * N2 + O + o];
    int js[KNN];
    #pragma unroll
    for (int k = 0; k < KNN; ++k) js[k] = idx[(size_t)p * KNN + k];
    float m = -INFINITY;
    #pragma unroll
    for (int k = 0; k < KNN; ++k) {
        float y = YZ[(size_t)(bbase + js[k]) * N2 + o];
        m = fmaxf(m, leaky((y + z) * s + bo));
    }
    cat[(size_t)p * CSTR + outOff + o] = m;
}

// ---------------- fused W5 matmul + bn + leaky + partial max/sum pool over n ----------------
// v3: 16-row x 4-col register blocking. Each thread computes cols 4t..4t+3 (float4 W loads),
// one 16-row stage per block -> each CAT tile staged once, 256 FMAs per c-group.
__global__ __launch_bounds__(256) void pool_w5_kernel(const float* __restrict__ cat, const float* __restrict__ W5t,
                                                      const float* __restrict__ g5, const float* __restrict__ b5,
                                                      float* __restrict__ pmax, float* __restrict__ psum) {
    __shared__ float rows[16][CSTR];   // 33.3 KB
    int b = blockIdx.x >> 7, nc = blockIdx.x & 127;   // 128 chunks of 16 rows
    int o4 = threadIdx.x * 4;
    for (int e = threadIdx.x; e < 16 * (CSTR / 4); e += 256) {
        int r = e / (CSTR / 4), cg = e - r * (CSTR / 4);
        *reinterpret_cast<float4*>(&rows[r][4 * cg]) =
            *reinterpret_cast<const float4*>(&cat[((size_t)b * NP + nc * 16 + r) * CSTR + 4 * cg]);
    }
    __syncthreads();
    float acc[4][16];
    #pragma unroll
    for (int j = 0; j < 4; ++j)
        #pragma unroll
        for (int r = 0; r < 16; ++r) acc[j][r] = 0.f;
    for (int c = 0; c < CSTR; c += 4) {
        float4 w0 = *reinterpret_cast<const float4*>(&W5t[(size_t)(c + 0) * 1024 + o4]);
        float4 w1 = *reinterpret_cast<const float4*>(&W5t[(size_t)(c + 1) * 1024 + o4]);
        float4 w2 = *reinterpret_cast<const float4*>(&W5t[(size_t)(c + 2) * 1024 + o4]);
        float4 w3 = *reinterpret_cast<const float4*>(&W5t[(size_t)(c + 3) * 1024 + o4]);
        #pragma unroll
        for (int r = 0; r < 16; ++r) {
            float4 rv = *reinterpret_cast<const float4*>(&rows[r][c]);
            acc[0][r] += rv.x * w0.x + rv.y * w1.x + rv.z * w2.x + rv.w * w3.x;
            acc[1][r] += rv.x * w0.y + rv.y * w1.y + rv.z * w2.y + rv.w * w3.y;
            acc[2][r] += rv.x * w0.z + rv.y * w1.z + rv.z * w2.z + rv.w * w3.z;
            acc[3][r] += rv.x * w0.w + rv.y * w1.w + rv.z * w2.w + rv.w * w3.w;
        }
    }
    const float bns = 1.0f / sqrtf(1.0f + 1e-5f);
    float4 gv = *reinterpret_cast<const float4*>(&g5[o4]);
    float4 bv = *reinterpret_cast<const float4*>(&b5[o4]);
    float gs[4] = {gv.x * bns, gv.y * bns, gv.z * bns, gv.w * bns};
    float bo[4] = {bv.x, bv.y, bv.z, bv.w};
    #pragma unroll
    for (int j = 0; j < 4; ++j) {
        float vmax = -INFINITY, vsum = 0.f;
        #pragma unroll
        for (int r = 0; r < 16; ++r) {
            float v = leaky(acc[j][r] * gs[j] + bo[j]);
            vmax = fmaxf(vmax, v); vsum += v;
        }
        pmax[((size_t)b * 1024 + o4 + j) * 128 + nc] = vmax;
        psum[((size_t)b * 1024 + o4 + j) * 128 + nc] = vsum;
    }
}

__global__ void pool_reduce_kernel(const float* __restrict__ pmax, const float* __restrict__ psum,
                                   float* __restrict__ f0) {
    int i = blockIdx.x * blockDim.x + threadIdx.x;
    if (i >= NB * 1024) return;
    int b = i >> 10, o = i & 1023;
    float m = -INFINITY, sm = 0.f;
    for (int nc = 0; nc < 128; ++nc) { m = fmaxf(m, pmax[(size_t)i * 128 + nc]); sm += psum[(size_t)i * 128 + nc]; }
    f0[(size_t)b * 2048 + o] = m;
    f0[(size_t)b * 2048 + 1024 + o] = sm * (1.0f / 2048.0f);
}

// ---------------- dense: one thread per (b, o) ----------------
__global__ void dense_kernel(const float* __restrict__ in, const float* __restrict__ W,
                             const float* __restrict__ bl, const float* __restrict__ g,
                             const float* __restrict__ bb, float* __restrict__ out,
                             int In, int Out, int act) {
    int i = blockIdx.x * blockDim.x + threadIdx.x;
    if (i >= NB * Out) return;
    int b = i / Out, o = i - b * Out;
    const float* w = W + (size_t)o * In;
    const float* xv = in + (size_t)b * In;
    float acc = 0.f;
    for (int c = 0; c < In; ++c) acc += xv[c] * w[c];
    acc += bl[o];
    if (act) {
        const float bns = 1.0f / sqrtf(1.0f + 1e-5f);
        acc = leaky(acc * (g[o] * bns) + bb[o]);
    }
    out[i] = acc;
}

extern "C" void kernel_launch(void* const* d_in, const int* in_sizes, int n_in,
                              void* d_out, int out_size, void* d_ws, size_t ws_size,
                              hipStream_t stream) {
    const float* x   = (const float*)d_in[0];
    const float* W1  = (const float*)d_in[2];
    const float* W2  = (const float*)d_in[3];
    const float* W3  = (const float*)d_in[4];
    const float* W4  = (const float*)d_in[5];
    const float* W5  = (const float*)d_in[6];
    const float* Wl1 = (const float*)d_in[7];
    const float* bl1 = (const float*)d_in[8];
    const float* Wl2 = (const float*)d_in[9];
    const float* bl2 = (const float*)d_in[10];
    const float* Wl3 = (const float*)d_in[11];
    const float* bl3 = (const float*)d_in[12];
    const float* g1 = (const float*)d_in[13]; const float* b1 = (const float*)d_in[14];
    const float* g2 = (const float*)d_in[15]; const float* b2 = (const float*)d_in[16];
    const float* g3 = (const float*)d_in[17]; const float* b3 = (const float*)d_in[18];
    const float* g4 = (const float*)d_in[19]; const float* b4 = (const float*)d_in[20];
    const float* g5 = (const float*)d_in[21]; const float* b5 = (const float*)d_in[22];
    const float* g6 = (const float*)d_in[23]; const float* bb6 = (const float*)d_in[24];
    const float* g7 = (const float*)d_in[25]; const float* bb7 = (const float*)d_in[26];

    float* ws = (float*)d_ws;
    size_t off = 0;
    float* CAT = ws + off; off += (size_t)NB * NP * CSTR;
    float* SQ  = ws + off; off += NB * NP;
    int*   IDX = (int*)(ws + off); off += (size_t)NB * NP * KNN;
    float* WYZ1 = ws + off; off += 4 * 128;
    float* WYZ2 = ws + off; off += 68 * 128;
    float* WYZ3 = ws + off; off += 132 * 256;
    float* WYZ4 = ws + off; off += 260 * 512;
    float* W5T = ws + off; off += 520 * 1024;
    float* BIG = ws + off;                    // shared region: DMAT+XT | YZ | pool buffers
    size_t wsfl = ws_size / 4;
    size_t avail = (wsfl > off) ? (wsfl - off) : 0;
    const size_t yzneed = (size_t)NB * NP * 512;
    int G = 1;
    for (int g = 8; g >= 1; g >>= 1) {
        size_t need = (size_t)g * NP * 2048 + (size_t)g * 128 * NP;   // DMAT + XT(K<=128)
        size_t big = (need > yzneed) ? need : yzneed;
        if (big <= avail) { G = g; break; }
    }
    float* DMAT = BIG;
    float* XT   = BIG + (size_t)G * NP * 2048;
    float* YZ   = BIG;
    float* PMAX = BIG;
    float* PSUM = PMAX + (size_t)NB * 1024 * 128;
    float* F0 = PSUM + (size_t)NB * 1024 * 128;
    float* F1 = F0 + NB * 2048;
    float* F2 = F1 + NB * 512;
    (void)in_sizes; (void)n_in; (void)out_size;

    dim3 b256(256);
    const int M16 = NB * NP / 16;   // 1024 row-blocks

    tx_kernel<<<(NB * NP + 255) / 256, b256, 0, stream>>>(x, CAT);
    buildWyz<<<(4 * 128 + 255) / 256, b256, 0, stream>>>(W1, WYZ1, 64, 3, 4);
    buildWyz<<<(68 * 128 + 255) / 256, b256, 0, stream>>>(W2, WYZ2, 64, 67, 68);
    buildWyz<<<(132 * 256 + 255) / 256, b256, 0, stream>>>(W3, WYZ3, 128, 131, 132);
    buildWyz<<<(260 * 512 + 255) / 256, b256, 0, stream>>>(W4, WYZ4, 256, 259, 260);
    transposeW5<<<(520 * 1024 + 255) / 256, b256, 0, stream>>>(W5, W5T);

    // macro-ish per-layer KNN: sqnorm -> (xt, distgemm, topk) per batch group
#define RUN_KNN(KK, OFFC)                                                                   \
    do {                                                                                    \
        sqnorm_kernel<<<(NB * NP + 255) / 256, b256, 0, stream>>>(CAT, OFFC, KK, SQ);       \
        for (int b0 = 0; b0 < NB; b0 += G) {                                                \
            xt_kernel<KK><<<dim3(G, NP / 64), b256, 0, stream>>>(CAT, OFFC, XT, b0);        \
            distgemm_kernel<KK><<<dim3(G * (NP / 16), NP / 512), b256, 0, stream>>>(        \
                CAT, OFFC, SQ, XT, DMAT, b0);                                               \
            topk_kernel<<<G * NP / 4, b256, 0, stream>>>(DMAT, IDX, b0);                    \
        }                                                                                   \
    } while (0)

    // layer 1: knn on xc (C=4 @0); GEMM over cols [0,4) -> N2=128; combine -> col 4
    RUN_KNN(4, 0);
    gemm_yz_kernel<4, 128><<<dim3(M16, 1), 128, 0, stream>>>(CAT, 0, WYZ1, 128, YZ);
    combine_kernel<64><<<NB * NP / 4, b256, 0, stream>>>(YZ, 128, IDX, g1, b1, CAT, 4);
    // layer 2: knn on x1 (C=64 @4); GEMM over cols [0,68); combine -> col 68
    RUN_KNN(64, 4);
    gemm_yz_kernel<68, 128><<<dim3(M16, 1), 128, 0, stream>>>(CAT, 0, WYZ2, 128, YZ);
    combine_kernel<64><<<NB * NP / 4, b256, 0, stream>>>(YZ, 128, IDX, g2, b2, CAT, 68);
    // layer 3: knn on x2 (C=64 @68); GEMM over cols [0,132); combine -> col 132
    RUN_KNN(64, 68);
    gemm_yz_kernel<132, 256><<<dim3(M16, 1), 256, 0, stream>>>(CAT, 0, WYZ3, 256, YZ);
    combine_kernel<128><<<NB * NP / 2, b256, 0, stream>>>(YZ, 256, IDX, g3, b3, CAT, 132);
    // layer 4: knn on x3 (C=128 @132); GEMM over cols [0,260); combine -> col 260
    RUN_KNN(128, 132);
    gemm_yz_kernel<260, 256><<<dim3(M16, 2), 256, 0, stream>>>(CAT, 0, WYZ4, 512, YZ);
    combine_kernel<256><<<NB * NP, b256, 0, stream>>>(YZ, 512, IDX, g4, b4, CAT, 260);
#undef RUN_KNN

    // W5 + bn + leaky + global max/mean pool
    pool_w5_kernel<<<NB * 128, b256, 0, stream>>>(CAT, W5T, g5, b5, PMAX, PSUM);
    pool_reduce_kernel<<<(NB * 1024 + 255) / 256, b256, 0, stream>>>(PMAX, PSUM, F0);

    // MLP head
    dense_kernel<<<(NB * 512 + 255) / 256, b256, 0, stream>>>(F0, Wl1, bl1, g6, bb6, F1, 2048, 512, 1);
    dense_kernel<<<(NB * 256 + 255) / 256, b256, 0, stream>>>(F1, Wl2, bl2, g7, bb7, F2, 512, 256, 1);
    dense_kernel<<<(NB * 40 + 255) / 256, b256, 0, stream>>>(F2, Wl3, bl3, nullptr, nullptr,
                                                             (float*)d_out, 256, 40, 0);
}

// Round 9
// 1417.207 us; speedup vs baseline: 22.6661x; 1.1608x over previous
//
#include <hip/hip_runtime.h>
#include <math.h>

#define NB 8
#define NP 2048
#define KNN 20
#define CSTR 520          // padded row stride of the cat feature buffer (floats)
#define NEG 0.2f
// padded column layout: [x:0..3)[pad:3][x1:4..68)[x2:68..132)[x3:132..260)[x4:260..516)

__device__ __forceinline__ float leaky(float x) { return x >= 0.0f ? x : NEG * x; }

// ---------------- transpose x (B,3,N) -> cat[:, :, 0:3], zero pad col 3 ----------------
__global__ void tx_kernel(const float* __restrict__ x, float* __restrict__ cat) {
    int i = blockIdx.x * blockDim.x + threadIdx.x;
    if (i >= NB * NP) return;
    int b = i / NP, n = i % NP;
    float* r = cat + (size_t)i * CSTR;
    r[0] = x[((size_t)b * 3 + 0) * NP + n];
    r[1] = x[((size_t)b * 3 + 1) * NP + n];
    r[2] = x[((size_t)b * 3 + 2) * NP + n];
    r[3] = 0.0f;
    r[516] = 0.f; r[517] = 0.f; r[518] = 0.f; r[519] = 0.f;
}

// ---------------- conv weights W (O, 2*Cin) -> Wyz (PC, 2*O): [Wd | Wc - Wd] ----------------
__global__ void buildWyz(const float* __restrict__ W, float* __restrict__ Wyz,
                         int O, int Cin, int PC) {
    int i = blockIdx.x * blockDim.x + threadIdx.x;
    int N2 = 2 * O;
    if (i >= PC * N2) return;
    int q = i / N2, n = i - q * N2;
    float v = 0.0f;
    if (q != 3) {
        int c = (q < 3) ? q : q - 1;
        if (c < Cin) {
            int o = (n < O) ? n : n - O;
            float wd = W[(size_t)o * (2 * Cin) + c];
            v = (n < O) ? wd : (W[(size_t)o * (2 * Cin) + Cin + c] - wd);
        }
    }
    Wyz[i] = v;
}

// ---------------- W5 (1024, 515) -> padded transposed W5t (520, 1024) ----------------
__global__ void transposeW5(const float* __restrict__ W, float* __restrict__ Wt) {
    int i = blockIdx.x * blockDim.x + threadIdx.x;
    if (i >= 520 * 1024) return;
    int p = i >> 10, o = i & 1023;
    float v = 0.0f;
    if (p < 516 && p != 3) {
        int c = (p < 3) ? p : p - 1;
        v = W[(size_t)o * 515 + c];
    }
    Wt[i] = v;
}

// ---------------- squared norms of feature slice (padded C, pad col is zero) ----------------
__global__ void sqnorm_kernel(const float* __restrict__ cat, int off, int C, float* __restrict__ sq) {
    int i = blockIdx.x * blockDim.x + threadIdx.x;
    if (i >= NB * NP) return;
    const float* f = cat + (size_t)i * CSTR + off;
    float s = 0.f;
    for (int c = 0; c < C; c += 4) {
        float4 v = *reinterpret_cast<const float4*>(f + c);
        s += v.x * v.x + v.y * v.y + v.z * v.z + v.w * v.w;
    }
    sq[i] = s;
}

// ---------------- XT: slice transpose cat[b][n][off+c] -> XT[bl][c][n] ----------------
template <int K>
__global__ __launch_bounds__(256) void xt_kernel(const float* __restrict__ cat, int off,
                                                 float* __restrict__ XT, int b0) {
    __shared__ float lds[64][K + 1];
    int bl = blockIdx.x;
    int b = b0 + bl;
    int n0 = blockIdx.y * 64;
    const float* src = cat + ((size_t)(b * NP + n0)) * CSTR + off;
    for (int e = threadIdx.x; e < 64 * (K / 4); e += 256) {
        int r = e / (K / 4), cg = e - r * (K / 4);
        float4 v = *reinterpret_cast<const float4*>(src + (size_t)r * CSTR + 4 * cg);
        lds[r][4 * cg + 0] = v.x; lds[r][4 * cg + 1] = v.y;
        lds[r][4 * cg + 2] = v.z; lds[r][4 * cg + 3] = v.w;
    }
    __syncthreads();
    float* dst = XT + (size_t)bl * K * NP;
    for (int e = threadIdx.x; e < 64 * K; e += 256) {
        int c = e >> 6, tn = e & 63;
        dst[(size_t)c * NP + n0 + tn] = lds[tn][c];
    }
}

// ---------------- distance GEMM v3: 16-row x 4-col register blocking ----------------
template <int K>
__global__ __launch_bounds__(256) void distgemm_kernel(const float* __restrict__ cat, int off,
                                                       const float* __restrict__ sq,
                                                       const float* __restrict__ XT,
                                                       float* __restrict__ D, int b0) {
    __shared__ float rows[16][K];
    int rb = blockIdx.x;
    int bl = rb / (NP / 16);
    int b = b0 + bl;
    int nb = (rb % (NP / 16)) * 16;
    int col = blockIdx.y * 1024 + threadIdx.x * 4;
    const float* src = cat + ((size_t)(b * NP + nb)) * CSTR + off;
    for (int e = threadIdx.x; e < 16 * (K / 4); e += 256) {
        int r = e / (K / 4), cg = e - r * (K / 4);
        *reinterpret_cast<float4*>(&rows[r][4 * cg]) =
            *reinterpret_cast<const float4*>(src + (size_t)r * CSTR + 4 * cg);
    }
    __syncthreads();
    const float* Wp = XT + (size_t)bl * K * NP;
    float acc[4][16];
    #pragma unroll
    for (int j = 0; j < 4; ++j)
        #pragma unroll
        for (int r = 0; r < 16; ++r) acc[j][r] = 0.f;
    for (int c = 0; c < K; c += 4) {
        float4 w0 = *reinterpret_cast<const float4*>(&Wp[(size_t)(c + 0) * NP + col]);
        float4 w1 = *reinterpret_cast<const float4*>(&Wp[(size_t)(c + 1) * NP + col]);
        float4 w2 = *reinterpret_cast<const float4*>(&Wp[(size_t)(c + 2) * NP + col]);
        float4 w3 = *reinterpret_cast<const float4*>(&Wp[(size_t)(c + 3) * NP + col]);
        #pragma unroll
        for (int r = 0; r < 16; ++r) {
            float4 rv = *reinterpret_cast<const float4*>(&rows[r][c]);
            acc[0][r] += rv.x * w0.x + rv.y * w1.x + rv.z * w2.x + rv.w * w3.x;
            acc[1][r] += rv.x * w0.y + rv.y * w1.y + rv.z * w2.y + rv.w * w3.y;
            acc[2][r] += rv.x * w0.z + rv.y * w1.z + rv.z * w2.z + rv.w * w3.z;
            acc[3][r] += rv.x * w0.w + rv.y * w1.w + rv.z * w2.w + rv.w * w3.w;
        }
    }
    float4 sqc = *reinterpret_cast<const float4*>(&sq[(size_t)b * NP + col]);
    float* drow = D + ((size_t)rb * 16) * NP + col;
    #pragma unroll
    for (int r = 0; r < 16; ++r) {
        float sqr = sq[(size_t)b * NP + nb + r];
        float4 outv = make_float4(2.f * acc[0][r] - sqr - sqc.x, 2.f * acc[1][r] - sqr - sqc.y,
                                  2.f * acc[2][r] - sqr - sqc.z, 2.f * acc[3][r] - sqr - sqc.w);
        *reinterpret_cast<float4*>(&drow[(size_t)r * NP]) = outv;
    }
}

// ---------------- top-k v2: register d[32] + selected-bitmask, no LDS ----------------
__global__ __launch_bounds__(256) void topk_kernel(const float* __restrict__ D,
                                                   int* __restrict__ idxout, int b0) {
    int wave = threadIdx.x >> 6, lane = threadIdx.x & 63;
    int ql = blockIdx.x * 4 + wave;      // group-local query row
    const float* drow = D + (size_t)ql * NP;
    float d[32];                          // static indexing only (fully unrolled)
    #pragma unroll
    for (int t = 0; t < 32; ++t) d[t] = drow[t * 64 + lane];
    unsigned sel = 0;                     // bit t set -> candidate t*64+lane already taken
    size_t q = (size_t)b0 * NP + ql;
    for (int k = 0; k < KNN; ++k) {
        float bv = -INFINITY; int bj = 0x7fffffff;
        #pragma unroll
        for (int t = 0; t < 32; ++t) {
            float v = (sel & (1u << t)) ? -INFINITY : d[t];
            if (v > bv) { bv = v; bj = t * 64 + lane; }   // ascending j; strict > keeps lowest
        }
        for (int s = 32; s; s >>= 1) {
            float ov = __shfl_xor(bv, s);
            int oj = __shfl_xor(bj, s);
            if (ov > bv || (ov == bv && oj < bj)) { bv = ov; bj = oj; }
        }
        if (lane == 0) idxout[q * KNN + k] = bj;
        if ((bj & 63) == lane) sel |= 1u << (bj >> 6);    // owner marks its slot
    }
}

// ---------------- YZ GEMM: YZ[p][:] = cat[p][0:K] @ Wyz (K x N2) ----------------
template <int K, int NT>
__global__ __launch_bounds__(NT) void gemm_yz_kernel(const float* __restrict__ cat, int off,
                                                     const float* __restrict__ W, int N2,
                                                     float* __restrict__ YZ) {
    __shared__ float rows[16][K];
    int col = blockIdx.y * NT + threadIdx.x;
    const float* src = cat + (size_t)blockIdx.x * 16 * CSTR + off;
    for (int e = threadIdx.x; e < 16 * (K / 4); e += NT) {
        int r = e / (K / 4), cg = e - r * (K / 4);
        *reinterpret_cast<float4*>(&rows[r][4 * cg]) =
            *reinterpret_cast<const float4*>(src + (size_t)r * CSTR + 4 * cg);
    }
    __syncthreads();
    float acc[16];
    #pragma unroll
    for (int r = 0; r < 16; ++r) acc[r] = 0.f;
    for (int c = 0; c < K; c += 4) {
        float w0 = W[(size_t)(c + 0) * N2 + col];
        float w1 = W[(size_t)(c + 1) * N2 + col];
        float w2 = W[(size_t)(c + 2) * N2 + col];
        float w3 = W[(size_t)(c + 3) * N2 + col];
        #pragma unroll
        for (int r = 0; r < 16; ++r) {
            float4 rv = *reinterpret_cast<const float4*>(&rows[r][c]);
            acc[r] += rv.x * w0 + rv.y * w1 + rv.z * w2 + rv.w * w3;
        }
    }
    float* dst = YZ + (size_t)blockIdx.x * 16 * N2 + col;
    #pragma unroll
    for (int r = 0; r < 16; ++r) dst[(size_t)r * N2] = acc[r];
}

// ---------------- combine: out[p][o] = max_k leaky((Y[j_k][o] + Z[p][o])*s + b) ----------------
template <int O>
__global__ __launch_bounds__(256) void combine_kernel(const float* __restrict__ YZ, int N2,
                                                      const int* __restrict__ idx,
                                                      const float* __restrict__ g,
                                                      const float* __restrict__ bias,
                                                      float* __restrict__ cat, int outOff) {
    constexpr int PPB = 256 / O;
    int sub = threadIdx.x / O, o = threadIdx.x % O;
    int p = blockIdx.x * PPB + sub;
    int bbase = p & ~(NP - 1);
    const float bns = 1.0f / sqrtf(1.0f + 1e-5f);
    float s = g[o] * bns, bo = bias[o];
    float z = YZ[(size_t)p * N2 + O + o];
    int js[KNN];
    #pragma unroll
    for (int k = 0; k < KNN; ++k) js[k] = idx[(size_t)p * KNN + k];
    float m = -INFINITY;
    #pragma unroll
    for (int k = 0; k < KNN; ++k) {
        float y = YZ[(size_t)(bbase + js[k]) * N2 + o];
        m = fmaxf(m, leaky((y + z) * s + bo));
    }
    cat[(size_t)p * CSTR + outOff + o] = m;
}

// ---------------- fused W5 matmul + pool, v4: 16 rows x 8 cols per thread ----------------
// 128 threads/block; each ds_read_b128 (broadcast) feeds 32 FMAs -> LDS pipe off critical path.
__global__ __launch_bounds__(128) void pool_w5_kernel(const float* __restrict__ cat, const float* __restrict__ W5t,
                                                      const float* __restrict__ g5, const float* __restrict__ b5,
                                                      float* __restrict__ pmax, float* __restrict__ psum) {
    __shared__ float rows[16][CSTR];   // 33.3 KB
    int b = blockIdx.x >> 7, nc = blockIdx.x & 127;   // 128 chunks of 16 rows
    int o8 = threadIdx.x * 8;
    for (int e = threadIdx.x; e < 16 * (CSTR / 4); e += 128) {
        int r = e / (CSTR / 4), cg = e - r * (CSTR / 4);
        *reinterpret_cast<float4*>(&rows[r][4 * cg]) =
            *reinterpret_cast<const float4*>(&cat[((size_t)b * NP + nc * 16 + r) * CSTR + 4 * cg]);
    }
    __syncthreads();
    float acc[16][8];
    #pragma unroll
    for (int r = 0; r < 16; ++r)
        #pragma unroll
        for (int j = 0; j < 8; ++j) acc[r][j] = 0.f;
    for (int c = 0; c < CSTR; c += 4) {
        float4 wa0 = *reinterpret_cast<const float4*>(&W5t[(size_t)(c + 0) * 1024 + o8]);
        float4 wb0 = *reinterpret_cast<const float4*>(&W5t[(size_t)(c + 0) * 1024 + o8 + 4]);
        float4 wa1 = *reinterpret_cast<const float4*>(&W5t[(size_t)(c + 1) * 1024 + o8]);
        float4 wb1 = *reinterpret_cast<const float4*>(&W5t[(size_t)(c + 1) * 1024 + o8 + 4]);
        float4 wa2 = *reinterpret_cast<const float4*>(&W5t[(size_t)(c + 2) * 1024 + o8]);
        float4 wb2 = *reinterpret_cast<const float4*>(&W5t[(size_t)(c + 2) * 1024 + o8 + 4]);
        float4 wa3 = *reinterpret_cast<const float4*>(&W5t[(size_t)(c + 3) * 1024 + o8]);
        float4 wb3 = *reinterpret_cast<const float4*>(&W5t[(size_t)(c + 3) * 1024 + o8 + 4]);
        #pragma unroll
        for (int r = 0; r < 16; ++r) {
            float4 rv = *reinterpret_cast<const float4*>(&rows[r][c]);
            acc[r][0] += rv.x * wa0.x + rv.y * wa1.x + rv.z * wa2.x + rv.w * wa3.x;
            acc[r][1] += rv.x * wa0.y + rv.y * wa1.y + rv.z * wa2.y + rv.w * wa3.y;
            acc[r][2] += rv.x * wa0.z + rv.y * wa1.z + rv.z * wa2.z + rv.w * wa3.z;
            acc[r][3] += rv.x * wa0.w + rv.y * wa1.w + rv.z * wa2.w + rv.w * wa3.w;
            acc[r][4] += rv.x * wb0.x + rv.y * wb1.x + rv.z * wb2.x + rv.w * wb3.x;
            acc[r][5] += rv.x * wb0.y + rv.y * wb1.y + rv.z * wb2.y + rv.w * wb3.y;
            acc[r][6] += rv.x * wb0.z + rv.y * wb1.z + rv.z * wb2.z + rv.w * wb3.z;
            acc[r][7] += rv.x * wb0.w + rv.y * wb1.w + rv.z * wb2.w + rv.w * wb3.w;
        }
    }
    const float bns = 1.0f / sqrtf(1.0f + 1e-5f);
    #pragma unroll
    for (int j = 0; j < 8; ++j) {
        float gs = g5[o8 + j] * bns, bo = b5[o8 + j];
        float vmax = -INFINITY, vsum = 0.f;
        #pragma unroll
        for (int r = 0; r < 16; ++r) {
            float v = leaky(acc[r][j] * gs + bo);
            vmax = fmaxf(vmax, v); vsum += v;
        }
        pmax[((size_t)b * 1024 + o8 + j) * 128 + nc] = vmax;
        psum[((size_t)b * 1024 + o8 + j) * 128 + nc] = vsum;
    }
}

__global__ void pool_reduce_kernel(const float* __restrict__ pmax, const float* __restrict__ psum,
                                   float* __restrict__ f0) {
    int i = blockIdx.x * blockDim.x + threadIdx.x;
    if (i >= NB * 1024) return;
    int b = i >> 10, o = i & 1023;
    float m = -INFINITY, sm = 0.f;
    for (int nc = 0; nc < 128; ++nc) { m = fmaxf(m, pmax[(size_t)i * 128 + nc]); sm += psum[(size_t)i * 128 + nc]; }
    f0[(size_t)b * 2048 + o] = m;
    f0[(size_t)b * 2048 + 1024 + o] = sm * (1.0f / 2048.0f);
}

// ---------------- dense: one thread per (b, o), float4 dot ----------------
__global__ void dense_kernel(const float* __restrict__ in, const float* __restrict__ W,
                             const float* __restrict__ bl, const float* __restrict__ g,
                             const float* __restrict__ bb, float* __restrict__ out,
                             int In, int Out, int act) {
    int i = blockIdx.x * blockDim.x + threadIdx.x;
    if (i >= NB * Out) return;
    int b = i / Out, o = i - b * Out;
    const float* w = W + (size_t)o * In;
    const float* xv = in + (size_t)b * In;
    float acc = 0.f;
    for (int c = 0; c < In; c += 4) {
        float4 a = *reinterpret_cast<const float4*>(&xv[c]);
        float4 v = *reinterpret_cast<const float4*>(&w[c]);
        acc += a.x * v.x + a.y * v.y + a.z * v.z + a.w * v.w;
    }
    acc += bl[o];
    if (act) {
        const float bns = 1.0f / sqrtf(1.0f + 1e-5f);
        acc = leaky(acc * (g[o] * bns) + bb[o]);
    }
    out[i] = acc;
}

extern "C" void kernel_launch(void* const* d_in, const int* in_sizes, int n_in,
                              void* d_out, int out_size, void* d_ws, size_t ws_size,
                              hipStream_t stream) {
    const float* x   = (const float*)d_in[0];
    const float* W1  = (const float*)d_in[2];
    const float* W2  = (const float*)d_in[3];
    const float* W3  = (const float*)d_in[4];
    const float* W4  = (const float*)d_in[5];
    const float* W5  = (const float*)d_in[6];
    const float* Wl1 = (const float*)d_in[7];
    const float* bl1 = (const float*)d_in[8];
    const float* Wl2 = (const float*)d_in[9];
    const float* bl2 = (const float*)d_in[10];
    const float* Wl3 = (const float*)d_in[11];
    const float* bl3 = (const float*)d_in[12];
    const float* g1 = (const float*)d_in[13]; const float* b1 = (const float*)d_in[14];
    const float* g2 = (const float*)d_in[15]; const float* b2 = (const float*)d_in[16];
    const float* g3 = (const float*)d_in[17]; const float* b3 = (const float*)d_in[18];
    const float* g4 = (const float*)d_in[19]; const float* b4 = (const float*)d_in[20];
    const float* g5 = (const float*)d_in[21]; const float* b5 = (const float*)d_in[22];
    const float* g6 = (const float*)d_in[23]; const float* bb6 = (const float*)d_in[24];
    const float* g7 = (const float*)d_in[25]; const float* bb7 = (const float*)d_in[26];

    float* ws = (float*)d_ws;
    size_t off = 0;
    float* CAT = ws + off; off += (size_t)NB * NP * CSTR;
    float* SQ  = ws + off; off += NB * NP;
    int*   IDX = (int*)(ws + off); off += (size_t)NB * NP * KNN;
    float* WYZ1 = ws + off; off += 4 * 128;
    float* WYZ2 = ws + off; off += 68 * 128;
    float* WYZ3 = ws + off; off += 132 * 256;
    float* WYZ4 = ws + off; off += 260 * 512;
    float* W5T = ws + off; off += 520 * 1024;
    float* BIG = ws + off;                    // shared region: DMAT+XT | YZ | pool buffers
    size_t wsfl = ws_size / 4;
    size_t avail = (wsfl > off) ? (wsfl - off) : 0;
    const size_t yzneed = (size_t)NB * NP * 512;
    int G = 1;
    for (int g = 8; g >= 1; g >>= 1) {
        size_t need = (size_t)g * NP * 2048 + (size_t)g * 128 * NP;   // DMAT + XT(K<=128)
        size_t big = (need > yzneed) ? need : yzneed;
        if (big <= avail) { G = g; break; }
    }
    float* DMAT = BIG;
    float* XT   = BIG + (size_t)G * NP * 2048;
    float* YZ   = BIG;
    float* PMAX = BIG;
    float* PSUM = PMAX + (size_t)NB * 1024 * 128;
    float* F0 = PSUM + (size_t)NB * 1024 * 128;
    float* F1 = F0 + NB * 2048;
    float* F2 = F1 + NB * 512;
    (void)in_sizes; (void)n_in; (void)out_size;

    dim3 b256(256);
    const int M16 = NB * NP / 16;   // 1024 row-blocks

    tx_kernel<<<(NB * NP + 255) / 256, b256, 0, stream>>>(x, CAT);
    buildWyz<<<(4 * 128 + 255) / 256, b256, 0, stream>>>(W1, WYZ1, 64, 3, 4);
    buildWyz<<<(68 * 128 + 255) / 256, b256, 0, stream>>>(W2, WYZ2, 64, 67, 68);
    buildWyz<<<(132 * 256 + 255) / 256, b256, 0, stream>>>(W3, WYZ3, 128, 131, 132);
    buildWyz<<<(260 * 512 + 255) / 256, b256, 0, stream>>>(W4, WYZ4, 256, 259, 260);
    transposeW5<<<(520 * 1024 + 255) / 256, b256, 0, stream>>>(W5, W5T);

#define RUN_KNN(KK, OFFC)                                                                   \
    do {                                                                                    \
        sqnorm_kernel<<<(NB * NP + 255) / 256, b256, 0, stream>>>(CAT, OFFC, KK, SQ);       \
        for (int b0 = 0; b0 < NB; b0 += G) {                                                \
            xt_kernel<KK><<<dim3(G, NP / 64), b256, 0, stream>>>(CAT, OFFC, XT, b0);        \
            distgemm_kernel<KK><<<dim3(G * (NP / 16), NP / 1024), b256, 0, stream>>>(       \
                CAT, OFFC, SQ, XT, DMAT, b0);                                               \
            topk_kernel<<<G * NP / 4, b256, 0, stream>>>(DMAT, IDX, b0);                    \
        }                                                                                   \
    } while (0)

    // layer 1
    RUN_KNN(4, 0);
    gemm_yz_kernel<4, 128><<<dim3(M16, 1), 128, 0, stream>>>(CAT, 0, WYZ1, 128, YZ);
    combine_kernel<64><<<NB * NP / 4, b256, 0, stream>>>(YZ, 128, IDX, g1, b1, CAT, 4);
    // layer 2
    RUN_KNN(64, 4);
    gemm_yz_kernel<68, 128><<<dim3(M16, 1), 128, 0, stream>>>(CAT, 0, WYZ2, 128, YZ);
    combine_kernel<64><<<NB * NP / 4, b256, 0, stream>>>(YZ, 128, IDX, g2, b2, CAT, 68);
    // layer 3
    RUN_KNN(64, 68);
    gemm_yz_kernel<132, 256><<<dim3(M16, 1), 256, 0, stream>>>(CAT, 0, WYZ3, 256, YZ);
    combine_kernel<128><<<NB * NP / 2, b256, 0, stream>>>(YZ, 256, IDX, g3, b3, CAT, 132);
    // layer 4
    RUN_KNN(128, 132);
    gemm_yz_kernel<260, 256><<<dim3(M16, 2), 256, 0, stream>>>(CAT, 0, WYZ4, 512, YZ);
    combine_kernel<256><<<NB * NP, b256, 0, stream>>>(YZ, 512, IDX, g4, b4, CAT, 260);
#undef RUN_KNN

    // W5 + bn + leaky + global max/mean pool
    pool_w5_kernel<<<NB * 128, 128, 0, stream>>>(CAT, W5T, g5, b5, PMAX, PSUM);
    pool_reduce_kernel<<<(NB * 1024 + 255) / 256, b256, 0, stream>>>(PMAX, PSUM, F0);

    // MLP head
    dense_kernel<<<(NB * 512 + 255) / 256, b256, 0, stream>>>(F0, Wl1, bl1, g6, bb6, F1, 2048, 512, 1);
    dense_kernel<<<(NB * 256 + 255) / 256, b256, 0, stream>>>(F1, Wl2, bl2, g7, bb7, F2, 512, 256, 1);
    dense_kernel<<<(NB * 40 + 255) / 256, b256, 0, stream>>>(F2, Wl3, bl3, nullptr, nullptr,
                                                             (float*)d_out, 256, 40, 0);
}

// Round 10
// 1411.494 us; speedup vs baseline: 22.7578x; 1.0040x over previous
//
#include <hip/hip_runtime.h>
#include <math.h>

#define NB 8
#define NP 2048
#define KNN 20
#define CSTR 520          // padded row stride of the cat feature buffer (floats)
#define NEG 0.2f
// padded column layout: [x:0..3)[pad:3][x1:4..68)[x2:68..132)[x3:132..260)[x4:260..516)

__device__ __forceinline__ float leaky(float x) { return x >= 0.0f ? x : NEG * x; }

// ---------------- transpose x (B,3,N) -> cat[:, :, 0:3], zero pad col 3 ----------------
__global__ void tx_kernel(const float* __restrict__ x, float* __restrict__ cat) {
    int i = blockIdx.x * blockDim.x + threadIdx.x;
    if (i >= NB * NP) return;
    int b = i / NP, n = i % NP;
    float* r = cat + (size_t)i * CSTR;
    r[0] = x[((size_t)b * 3 + 0) * NP + n];
    r[1] = x[((size_t)b * 3 + 1) * NP + n];
    r[2] = x[((size_t)b * 3 + 2) * NP + n];
    r[3] = 0.0f;
    r[516] = 0.f; r[517] = 0.f; r[518] = 0.f; r[519] = 0.f;
}

// ---------------- conv weights W (O, 2*Cin) -> Wyz (PC, 2*O): [Wd | Wc - Wd] ----------------
__global__ void buildWyz(const float* __restrict__ W, float* __restrict__ Wyz,
                         int O, int Cin, int PC) {
    int i = blockIdx.x * blockDim.x + threadIdx.x;
    int N2 = 2 * O;
    if (i >= PC * N2) return;
    int q = i / N2, n = i - q * N2;
    float v = 0.0f;
    if (q != 3) {
        int c = (q < 3) ? q : q - 1;
        if (c < Cin) {
            int o = (n < O) ? n : n - O;
            float wd = W[(size_t)o * (2 * Cin) + c];
            v = (n < O) ? wd : (W[(size_t)o * (2 * Cin) + Cin + c] - wd);
        }
    }
    Wyz[i] = v;
}

// ---------------- W5 (1024, 515) -> padded transposed W5t (520, 1024) ----------------
__global__ void transposeW5(const float* __restrict__ W, float* __restrict__ Wt) {
    int i = blockIdx.x * blockDim.x + threadIdx.x;
    if (i >= 520 * 1024) return;
    int p = i >> 10, o = i & 1023;
    float v = 0.0f;
    if (p < 516 && p != 3) {
        int c = (p < 3) ? p : p - 1;
        v = W[(size_t)o * 515 + c];
    }
    Wt[i] = v;
}

// ---------------- squared norms of feature slice (padded C, pad col is zero) ----------------
__global__ void sqnorm_kernel(const float* __restrict__ cat, int off, int C, float* __restrict__ sq) {
    int i = blockIdx.x * blockDim.x + threadIdx.x;
    if (i >= NB * NP) return;
    const float* f = cat + (size_t)i * CSTR + off;
    float s = 0.f;
    for (int c = 0; c < C; c += 4) {
        float4 v = *reinterpret_cast<const float4*>(f + c);
        s += v.x * v.x + v.y * v.y + v.z * v.z + v.w * v.w;
    }
    sq[i] = s;
}

// ---------------- XT: slice transpose cat[b][n][off+c] -> XT[bl][c][n] ----------------
template <int K>
__global__ __launch_bounds__(256) void xt_kernel(const float* __restrict__ cat, int off,
                                                 float* __restrict__ XT, int b0) {
    __shared__ float lds[64][K + 1];
    int bl = blockIdx.x;
    int b = b0 + bl;
    int n0 = blockIdx.y * 64;
    const float* src = cat + ((size_t)(b * NP + n0)) * CSTR + off;
    for (int e = threadIdx.x; e < 64 * (K / 4); e += 256) {
        int r = e / (K / 4), cg = e - r * (K / 4);
        float4 v = *reinterpret_cast<const float4*>(src + (size_t)r * CSTR + 4 * cg);
        lds[r][4 * cg + 0] = v.x; lds[r][4 * cg + 1] = v.y;
        lds[r][4 * cg + 2] = v.z; lds[r][4 * cg + 3] = v.w;
    }
    __syncthreads();
    float* dst = XT + (size_t)bl * K * NP;
    for (int e = threadIdx.x; e < 64 * K; e += 256) {
        int c = e >> 6, tn = e & 63;
        dst[(size_t)c * NP + n0 + tn] = lds[tn][c];
    }
}

// ---------------- distance GEMM v3: 16-row x 4-col register blocking ----------------
template <int K>
__global__ __launch_bounds__(256) void distgemm_kernel(const float* __restrict__ cat, int off,
                                                       const float* __restrict__ sq,
                                                       const float* __restrict__ XT,
                                                       float* __restrict__ D, int b0) {
    __shared__ float rows[16][K];
    int rb = blockIdx.x;
    int bl = rb / (NP / 16);
    int b = b0 + bl;
    int nb = (rb % (NP / 16)) * 16;
    int col = blockIdx.y * 1024 + threadIdx.x * 4;
    const float* src = cat + ((size_t)(b * NP + nb)) * CSTR + off;
    for (int e = threadIdx.x; e < 16 * (K / 4); e += 256) {
        int r = e / (K / 4), cg = e - r * (K / 4);
        *reinterpret_cast<float4*>(&rows[r][4 * cg]) =
            *reinterpret_cast<const float4*>(src + (size_t)r * CSTR + 4 * cg);
    }
    __syncthreads();
    const float* Wp = XT + (size_t)bl * K * NP;
    float acc[4][16];
    #pragma unroll
    for (int j = 0; j < 4; ++j)
        #pragma unroll
        for (int r = 0; r < 16; ++r) acc[j][r] = 0.f;
    for (int c = 0; c < K; c += 4) {
        float4 w0 = *reinterpret_cast<const float4*>(&Wp[(size_t)(c + 0) * NP + col]);
        float4 w1 = *reinterpret_cast<const float4*>(&Wp[(size_t)(c + 1) * NP + col]);
        float4 w2 = *reinterpret_cast<const float4*>(&Wp[(size_t)(c + 2) * NP + col]);
        float4 w3 = *reinterpret_cast<const float4*>(&Wp[(size_t)(c + 3) * NP + col]);
        #pragma unroll
        for (int r = 0; r < 16; ++r) {
            float4 rv = *reinterpret_cast<const float4*>(&rows[r][c]);
            acc[0][r] += rv.x * w0.x + rv.y * w1.x + rv.z * w2.x + rv.w * w3.x;
            acc[1][r] += rv.x * w0.y + rv.y * w1.y + rv.z * w2.y + rv.w * w3.y;
            acc[2][r] += rv.x * w0.z + rv.y * w1.z + rv.z * w2.z + rv.w * w3.z;
            acc[3][r] += rv.x * w0.w + rv.y * w1.w + rv.z * w2.w + rv.w * w3.w;
        }
    }
    float4 sqc = *reinterpret_cast<const float4*>(&sq[(size_t)b * NP + col]);
    float* drow = D + ((size_t)rb * 16) * NP + col;
    #pragma unroll
    for (int r = 0; r < 16; ++r) {
        float sqr = sq[(size_t)b * NP + nb + r];
        float4 outv = make_float4(2.f * acc[0][r] - sqr - sqc.x, 2.f * acc[1][r] - sqr - sqc.y,
                                  2.f * acc[2][r] - sqr - sqc.z, 2.f * acc[3][r] - sqr - sqc.w);
        *reinterpret_cast<float4*>(&drow[(size_t)r * NP]) = outv;
    }
}

// ---------------- top-k v2: register d[32] + selected-bitmask, no LDS ----------------
__global__ __launch_bounds__(256) void topk_kernel(const float* __restrict__ D,
                                                   int* __restrict__ idxout, int b0) {
    int wave = threadIdx.x >> 6, lane = threadIdx.x & 63;
    int ql = blockIdx.x * 4 + wave;
    const float* drow = D + (size_t)ql * NP;
    float d[32];
    #pragma unroll
    for (int t = 0; t < 32; ++t) d[t] = drow[t * 64 + lane];
    unsigned sel = 0;
    size_t q = (size_t)b0 * NP + ql;
    for (int k = 0; k < KNN; ++k) {
        float bv = -INFINITY; int bj = 0x7fffffff;
        #pragma unroll
        for (int t = 0; t < 32; ++t) {
            float v = (sel & (1u << t)) ? -INFINITY : d[t];
            if (v > bv) { bv = v; bj = t * 64 + lane; }
        }
        for (int s = 32; s; s >>= 1) {
            float ov = __shfl_xor(bv, s);
            int oj = __shfl_xor(bj, s);
            if (ov > bv || (ov == bv && oj < bj)) { bv = ov; bj = oj; }
        }
        if (lane == 0) idxout[q * KNN + k] = bj;
        if ((bj & 63) == lane) sel |= 1u << (bj >> 6);
    }
}

// ---------------- YZ GEMM: YZ[p][col0..col0+NO) = cat[p][0:K] @ Wyz ----------------
// NO cols per thread, acc[16][NO] <= 64 regs (proven shape).
template <int K, int NT, int NO>
__global__ __launch_bounds__(NT) void gemm_yz_kernel(const float* __restrict__ cat, int off,
                                                     const float* __restrict__ W, int N2,
                                                     float* __restrict__ YZ) {
    __shared__ float rows[16][K];
    int col = (blockIdx.y * NT + threadIdx.x) * NO;
    const float* src = cat + (size_t)blockIdx.x * 16 * CSTR + off;
    for (int e = threadIdx.x; e < 16 * (K / 4); e += NT) {
        int r = e / (K / 4), cg = e - r * (K / 4);
        *reinterpret_cast<float4*>(&rows[r][4 * cg]) =
            *reinterpret_cast<const float4*>(src + (size_t)r * CSTR + 4 * cg);
    }
    __syncthreads();
    float acc[16][NO];
    #pragma unroll
    for (int r = 0; r < 16; ++r)
        #pragma unroll
        for (int j = 0; j < NO; ++j) acc[r][j] = 0.f;
    for (int c = 0; c < K; c += 4) {
        float wv[4][NO];
        #pragma unroll
        for (int i = 0; i < 4; ++i) {
            if constexpr (NO == 4) {
                float4 w = *reinterpret_cast<const float4*>(&W[(size_t)(c + i) * N2 + col]);
                wv[i][0] = w.x; wv[i][1] = w.y; wv[i][2] = w.z; wv[i][3] = w.w;
            } else if constexpr (NO == 2) {
                float2 w = *reinterpret_cast<const float2*>(&W[(size_t)(c + i) * N2 + col]);
                wv[i][0] = w.x; wv[i][1] = w.y;
            } else {
                wv[i][0] = W[(size_t)(c + i) * N2 + col];
            }
        }
        #pragma unroll
        for (int r = 0; r < 16; ++r) {
            float4 rv = *reinterpret_cast<const float4*>(&rows[r][c]);
            #pragma unroll
            for (int j = 0; j < NO; ++j)
                acc[r][j] += rv.x * wv[0][j] + rv.y * wv[1][j] + rv.z * wv[2][j] + rv.w * wv[3][j];
        }
    }
    #pragma unroll
    for (int r = 0; r < 16; ++r) {
        float* dst = YZ + ((size_t)blockIdx.x * 16 + r) * N2 + col;
        if constexpr (NO == 4) {
            *reinterpret_cast<float4*>(dst) = make_float4(acc[r][0], acc[r][1], acc[r][2], acc[r][3]);
        } else if constexpr (NO == 2) {
            *reinterpret_cast<float2*>(dst) = make_float2(acc[r][0], acc[r][1]);
        } else {
            dst[0] = acc[r][0];
        }
    }
}

// ---------------- combine: out[p][o] = max_k leaky((Y[j_k][o] + Z[p][o])*s + b) ----------------
template <int O>
__global__ __launch_bounds__(256) void combine_kernel(const float* __restrict__ YZ, int N2,
                                                      const int* __restrict__ idx,
                                                      const float* __restrict__ g,
                                                      const float* __restrict__ bias,
                                                      float* __restrict__ cat, int outOff) {
    constexpr int PPB = 256 / O;
    int sub = threadIdx.x / O, o = threadIdx.x % O;
    int p = blockIdx.x * PPB + sub;
    int bbase = p & ~(NP - 1);
    const float bns = 1.0f / sqrtf(1.0f + 1e-5f);
    float s = g[o] * bns, bo = bias[o];
    float z = YZ[(size_t)p * N2 + O + o];
    int js[KNN];
    #pragma unroll
    for (int k = 0; k < KNN; ++k) js[k] = idx[(size_t)p * KNN + k];
    float m = -INFINITY;
    #pragma unroll
    for (int k = 0; k < KNN; ++k) {
        float y = YZ[(size_t)(bbase + js[k]) * N2 + o];
        m = fmaxf(m, leaky((y + z) * s + bo));
    }
    cat[(size_t)p * CSTR + outOff + o] = m;
}

// ---------------- fused W5 matmul + pool, v5: 8 rows x 8 cols per thread ----------------
// 256 threads = 2 row-halves x 128 col-threads; block tile 16 x 1024.
// acc[8][8] = 64 regs (proven count); 8 ds_read_b128 per c-group feed 256 FMAs.
__global__ __launch_bounds__(256) void pool_w5_kernel(const float* __restrict__ cat, const float* __restrict__ W5t,
                                                      const float* __restrict__ g5, const float* __restrict__ b5,
                                                      float* __restrict__ pmax, float* __restrict__ psum) {
    __shared__ float rows[16][CSTR];   // 33.3 KB
    int b = blockIdx.x >> 7, nc = blockIdx.x & 127;   // 128 chunks of 16 rows
    int ty = threadIdx.x >> 7;         // row half: rows ty*8 .. ty*8+7
    int tx = threadIdx.x & 127;
    int o8 = tx * 8;
    for (int e = threadIdx.x; e < 16 * (CSTR / 4); e += 256) {
        int r = e / (CSTR / 4), cg = e - r * (CSTR / 4);
        *reinterpret_cast<float4*>(&rows[r][4 * cg]) =
            *reinterpret_cast<const float4*>(&cat[((size_t)b * NP + nc * 16 + r) * CSTR + 4 * cg]);
    }
    __syncthreads();
    float acc[8][8];
    #pragma unroll
    for (int r = 0; r < 8; ++r)
        #pragma unroll
        for (int j = 0; j < 8; ++j) acc[r][j] = 0.f;
    const int r0 = ty * 8;
    for (int c = 0; c < CSTR; c += 4) {
        float4 wa0 = *reinterpret_cast<const float4*>(&W5t[(size_t)(c + 0) * 1024 + o8]);
        float4 wb0 = *reinterpret_cast<const float4*>(&W5t[(size_t)(c + 0) * 1024 + o8 + 4]);
        float4 wa1 = *reinterpret_cast<const float4*>(&W5t[(size_t)(c + 1) * 1024 + o8]);
        float4 wb1 = *reinterpret_cast<const float4*>(&W5t[(size_t)(c + 1) * 1024 + o8 + 4]);
        float4 wa2 = *reinterpret_cast<const float4*>(&W5t[(size_t)(c + 2) * 1024 + o8]);
        float4 wb2 = *reinterpret_cast<const float4*>(&W5t[(size_t)(c + 2) * 1024 + o8 + 4]);
        float4 wa3 = *reinterpret_cast<const float4*>(&W5t[(size_t)(c + 3) * 1024 + o8]);
        float4 wb3 = *reinterpret_cast<const float4*>(&W5t[(size_t)(c + 3) * 1024 + o8 + 4]);
        #pragma unroll
        for (int r = 0; r < 8; ++r) {
            float4 rv = *reinterpret_cast<const float4*>(&rows[r0 + r][c]);
            acc[r][0] += rv.x * wa0.x + rv.y * wa1.x + rv.z * wa2.x + rv.w * wa3.x;
            acc[r][1] += rv.x * wa0.y + rv.y * wa1.y + rv.z * wa2.y + rv.w * wa3.y;
            acc[r][2] += rv.x * wa0.z + rv.y * wa1.z + rv.z * wa2.z + rv.w * wa3.z;
            acc[r][3] += rv.x * wa0.w + rv.y * wa1.w + rv.z * wa2.w + rv.w * wa3.w;
            acc[r][4] += rv.x * wb0.x + rv.y * wb1.x + rv.z * wb2.x + rv.w * wb3.x;
            acc[r][5] += rv.x * wb0.y + rv.y * wb1.y + rv.z * wb2.y + rv.w * wb3.y;
            acc[r][6] += rv.x * wb0.z + rv.y * wb1.z + rv.z * wb2.z + rv.w * wb3.z;
            acc[r][7] += rv.x * wb0.w + rv.y * wb1.w + rv.z * wb2.w + rv.w * wb3.w;
        }
    }
    const float bns = 1.0f / sqrtf(1.0f + 1e-5f);
    int chunk = nc * 2 + ty;           // 256 chunks of 8 rows
    #pragma unroll
    for (int j = 0; j < 8; ++j) {
        float gs = g5[o8 + j] * bns, bo = b5[o8 + j];
        float vmax = -INFINITY, vsum = 0.f;
        #pragma unroll
        for (int r = 0; r < 8; ++r) {
            float v = leaky(acc[r][j] * gs + bo);
            vmax = fmaxf(vmax, v); vsum += v;
        }
        pmax[((size_t)b * 1024 + o8 + j) * 256 + chunk] = vmax;
        psum[((size_t)b * 1024 + o8 + j) * 256 + chunk] = vsum;
    }
}

__global__ void pool_reduce_kernel(const float* __restrict__ pmax, const float* __restrict__ psum,
                                   float* __restrict__ f0) {
    int i = blockIdx.x * blockDim.x + threadIdx.x;
    if (i >= NB * 1024) return;
    int b = i >> 10, o = i & 1023;
    float m = -INFINITY, sm = 0.f;
    for (int nc = 0; nc < 256; ++nc) { m = fmaxf(m, pmax[(size_t)i * 256 + nc]); sm += psum[(size_t)i * 256 + nc]; }
    f0[(size_t)b * 2048 + o] = m;
    f0[(size_t)b * 2048 + 1024 + o] = sm * (1.0f / 2048.0f);
}

// ---------------- dense: one thread per (b, o), float4 dot ----------------
__global__ void dense_kernel(const float* __restrict__ in, const float* __restrict__ W,
                             const float* __restrict__ bl, const float* __restrict__ g,
                             const float* __restrict__ bb, float* __restrict__ out,
                             int In, int Out, int act) {
    int i = blockIdx.x * blockDim.x + threadIdx.x;
    if (i >= NB * Out) return;
    int b = i / Out, o = i - b * Out;
    const float* w = W + (size_t)o * In;
    const float* xv = in + (size_t)b * In;
    float acc = 0.f;
    for (int c = 0; c < In; c += 4) {
        float4 a = *reinterpret_cast<const float4*>(&xv[c]);
        float4 v = *reinterpret_cast<const float4*>(&w[c]);
        acc += a.x * v.x + a.y * v.y + a.z * v.z + a.w * v.w;
    }
    acc += bl[o];
    if (act) {
        const float bns = 1.0f / sqrtf(1.0f + 1e-5f);
        acc = leaky(acc * (g[o] * bns) + bb[o]);
    }
    out[i] = acc;
}

extern "C" void kernel_launch(void* const* d_in, const int* in_sizes, int n_in,
                              void* d_out, int out_size, void* d_ws, size_t ws_size,
                              hipStream_t stream) {
    const float* x   = (const float*)d_in[0];
    const float* W1  = (const float*)d_in[2];
    const float* W2  = (const float*)d_in[3];
    const float* W3  = (const float*)d_in[4];
    const float* W4  = (const float*)d_in[5];
    const float* W5  = (const float*)d_in[6];
    const float* Wl1 = (const float*)d_in[7];
    const float* bl1 = (const float*)d_in[8];
    const float* Wl2 = (const float*)d_in[9];
    const float* bl2 = (const float*)d_in[10];
    const float* Wl3 = (const float*)d_in[11];
    const float* bl3 = (const float*)d_in[12];
    const float* g1 = (const float*)d_in[13]; const float* b1 = (const float*)d_in[14];
    const float* g2 = (const float*)d_in[15]; const float* b2 = (const float*)d_in[16];
    const float* g3 = (const float*)d_in[17]; const float* b3 = (const float*)d_in[18];
    const float* g4 = (const float*)d_in[19]; const float* b4 = (const float*)d_in[20];
    const float* g5 = (const float*)d_in[21]; const float* b5 = (const float*)d_in[22];
    const float* g6 = (const float*)d_in[23]; const float* bb6 = (const float*)d_in[24];
    const float* g7 = (const float*)d_in[25]; const float* bb7 = (const float*)d_in[26];

    float* ws = (float*)d_ws;
    size_t off = 0;
    float* CAT = ws + off; off += (size_t)NB * NP * CSTR;
    float* SQ  = ws + off; off += NB * NP;
    int*   IDX = (int*)(ws + off); off += (size_t)NB * NP * KNN;
    float* WYZ1 = ws + off; off += 4 * 128;
    float* WYZ2 = ws + off; off += 68 * 128;
    float* WYZ3 = ws + off; off += 132 * 256;
    float* WYZ4 = ws + off; off += 260 * 512;
    float* W5T = ws + off; off += 520 * 1024;
    float* BIG = ws + off;                    // shared region: DMAT+XT | YZ | pool buffers
    size_t wsfl = ws_size / 4;
    size_t avail = (wsfl > off) ? (wsfl - off) : 0;
    const size_t yzneed = (size_t)NB * NP * 512;
    int G = 1;
    for (int g = 8; g >= 1; g >>= 1) {
        size_t need = (size_t)g * NP * 2048 + (size_t)g * 128 * NP;   // DMAT + XT(K<=128)
        size_t big = (need > yzneed) ? need : yzneed;
        if (big <= avail) { G = g; break; }
    }
    float* DMAT = BIG;
    float* XT   = BIG + (size_t)G * NP * 2048;
    float* YZ   = BIG;
    float* PMAX = BIG;
    float* PSUM = PMAX + (size_t)NB * 1024 * 256;
    float* F0 = PSUM + (size_t)NB * 1024 * 256;
    float* F1 = F0 + NB * 2048;
    float* F2 = F1 + NB * 512;
    (void)in_sizes; (void)n_in; (void)out_size;

    dim3 b256(256);
    const int M16 = NB * NP / 16;   // 1024 row-blocks

    tx_kernel<<<(NB * NP + 255) / 256, b256, 0, stream>>>(x, CAT);
    buildWyz<<<(4 * 128 + 255) / 256, b256, 0, stream>>>(W1, WYZ1, 64, 3, 4);
    buildWyz<<<(68 * 128 + 255) / 256, b256, 0, stream>>>(W2, WYZ2, 64, 67, 68);
    buildWyz<<<(132 * 256 + 255) / 256, b256, 0, stream>>>(W3, WYZ3, 128, 131, 132);
    buildWyz<<<(260 * 512 + 255) / 256, b256, 0, stream>>>(W4, WYZ4, 256, 259, 260);
    transposeW5<<<(520 * 1024 + 255) / 256, b256, 0, stream>>>(W5, W5T);

#define RUN_KNN(KK, OFFC)                                                                   \
    do {                                                                                    \
        sqnorm_kernel<<<(NB * NP + 255) / 256, b256, 0, stream>>>(CAT, OFFC, KK, SQ);       \
        for (int b0 = 0; b0 < NB; b0 += G) {                                                \
            xt_kernel<KK><<<dim3(G, NP / 64), b256, 0, stream>>>(CAT, OFFC, XT, b0);        \
            distgemm_kernel<KK><<<dim3(G * (NP / 16), NP / 1024), b256, 0, stream>>>(       \
                CAT, OFFC, SQ, XT, DMAT, b0);                                               \
            topk_kernel<<<G * NP / 4, b256, 0, stream>>>(DMAT, IDX, b0);                    \
        }                                                                                   \
    } while (0)

    // layer 1
    RUN_KNN(4, 0);
    gemm_yz_kernel<4, 128, 1><<<dim3(M16, 1), 128, 0, stream>>>(CAT, 0, WYZ1, 128, YZ);
    combine_kernel<64><<<NB * NP / 4, b256, 0, stream>>>(YZ, 128, IDX, g1, b1, CAT, 4);
    // layer 2
    RUN_KNN(64, 4);
    gemm_yz_kernel<68, 128, 1><<<dim3(M16, 1), 128, 0, stream>>>(CAT, 0, WYZ2, 128, YZ);
    combine_kernel<64><<<NB * NP / 4, b256, 0, stream>>>(YZ, 128, IDX, g2, b2, CAT, 68);
    // layer 3
    RUN_KNN(64, 68);
    gemm_yz_kernel<132, 128, 2><<<dim3(M16, 1), 128, 0, stream>>>(CAT, 0, WYZ3, 256, YZ);
    combine_kernel<128><<<NB * NP / 2, b256, 0, stream>>>(YZ, 256, IDX, g3, b3, CAT, 132);
    // layer 4
    RUN_KNN(128, 132);
    gemm_yz_kernel<260, 128, 4><<<dim3(M16, 1), 128, 0, stream>>>(CAT, 0, WYZ4, 512, YZ);
    combine_kernel<256><<<NB * NP, b256, 0, stream>>>(YZ, 512, IDX, g4, b4, CAT, 260);
#undef RUN_KNN

    // W5 + bn + leaky + global max/mean pool
    pool_w5_kernel<<<NB * 128, b256, 0, stream>>>(CAT, W5T, g5, b5, PMAX, PSUM);
    pool_reduce_kernel<<<(NB * 1024 + 255) / 256, b256, 0, stream>>>(PMAX, PSUM, F0);

    // MLP head
    dense_kernel<<<(NB * 512 + 255) / 256, b256, 0, stream>>>(F0, Wl1, bl1, g6, bb6, F1, 2048, 512, 1);
    dense_kernel<<<(NB * 256 + 255) / 256, b256, 0, stream>>>(F1, Wl2, bl2, g7, bb7, F2, 512, 256, 1);
    dense_kernel<<<(NB * 40 + 255) / 256, b256, 0, stream>>>(F2, Wl3, bl3, nullptr, nullptr,
                                                             (float*)d_out, 256, 40, 0);
}

// Round 11
// 1407.116 us; speedup vs baseline: 22.8287x; 1.0031x over previous
//
#include <hip/hip_runtime.h>
#include <math.h>

#define NB 8
#define NP 2048
#define KNN 20
#define CSTR 520          // padded row stride of the cat feature buffer (floats)
#define NEG 0.2f
// padded column layout: [x:0..3)[pad:3][x1:4..68)[x2:68..132)[x3:132..260)[x4:260..516)

__device__ __forceinline__ float leaky(float x) { return x >= 0.0f ? x : NEG * x; }

// ---------------- transpose x (B,3,N) -> cat[:, :, 0:3], zero pad col 3 ----------------
__global__ void tx_kernel(const float* __restrict__ x, float* __restrict__ cat) {
    int i = blockIdx.x * blockDim.x + threadIdx.x;
    if (i >= NB * NP) return;
    int b = i / NP, n = i % NP;
    float* r = cat + (size_t)i * CSTR;
    r[0] = x[((size_t)b * 3 + 0) * NP + n];
    r[1] = x[((size_t)b * 3 + 1) * NP + n];
    r[2] = x[((size_t)b * 3 + 2) * NP + n];
    r[3] = 0.0f;
    r[516] = 0.f; r[517] = 0.f; r[518] = 0.f; r[519] = 0.f;
}

// ---------------- conv weights W (O, 2*Cin) -> Wyz (PC, 2*O): [Wd | Wc - Wd] ----------------
__global__ void buildWyz(const float* __restrict__ W, float* __restrict__ Wyz,
                         int O, int Cin, int PC) {
    int i = blockIdx.x * blockDim.x + threadIdx.x;
    int N2 = 2 * O;
    if (i >= PC * N2) return;
    int q = i / N2, n = i - q * N2;
    float v = 0.0f;
    if (q != 3) {
        int c = (q < 3) ? q : q - 1;
        if (c < Cin) {
            int o = (n < O) ? n : n - O;
            float wd = W[(size_t)o * (2 * Cin) + c];
            v = (n < O) ? wd : (W[(size_t)o * (2 * Cin) + Cin + c] - wd);
        }
    }
    Wyz[i] = v;
}

// ---------------- W5 (1024, 515) -> padded transposed W5t (520, 1024) ----------------
__global__ void transposeW5(const float* __restrict__ W, float* __restrict__ Wt) {
    int i = blockIdx.x * blockDim.x + threadIdx.x;
    if (i >= 520 * 1024) return;
    int p = i >> 10, o = i & 1023;
    float v = 0.0f;
    if (p < 516 && p != 3) {
        int c = (p < 3) ? p : p - 1;
        v = W[(size_t)o * 515 + c];
    }
    Wt[i] = v;
}

// ---------------- squared norms of feature slice (padded C, pad col is zero) ----------------
__global__ void sqnorm_kernel(const float* __restrict__ cat, int off, int C, float* __restrict__ sq) {
    int i = blockIdx.x * blockDim.x + threadIdx.x;
    if (i >= NB * NP) return;
    const float* f = cat + (size_t)i * CSTR + off;
    float s = 0.f;
    for (int c = 0; c < C; c += 4) {
        float4 v = *reinterpret_cast<const float4*>(f + c);
        s += v.x * v.x + v.y * v.y + v.z * v.z + v.w * v.w;
    }
    sq[i] = s;
}

// ---------------- XT: slice transpose cat[b][n][off+c] -> XT[bl][c][n] ----------------
template <int K>
__global__ __launch_bounds__(256) void xt_kernel(const float* __restrict__ cat, int off,
                                                 float* __restrict__ XT, int b0) {
    __shared__ float lds[64][K + 1];
    int bl = blockIdx.x;
    int b = b0 + bl;
    int n0 = blockIdx.y * 64;
    const float* src = cat + ((size_t)(b * NP + n0)) * CSTR + off;
    for (int e = threadIdx.x; e < 64 * (K / 4); e += 256) {
        int r = e / (K / 4), cg = e - r * (K / 4);
        float4 v = *reinterpret_cast<const float4*>(src + (size_t)r * CSTR + 4 * cg);
        lds[r][4 * cg + 0] = v.x; lds[r][4 * cg + 1] = v.y;
        lds[r][4 * cg + 2] = v.z; lds[r][4 * cg + 3] = v.w;
    }
    __syncthreads();
    float* dst = XT + (size_t)bl * K * NP;
    for (int e = threadIdx.x; e < 64 * K; e += 256) {
        int c = e >> 6, tn = e & 63;
        dst[(size_t)c * NP + n0 + tn] = lds[tn][c];
    }
}

// ---------------- distance GEMM v3: 16-row x 4-col register blocking ----------------
// amdgpu_waves_per_eu(2): raise VGPR budget to 256 so the 64-acc tile stays in registers.
template <int K>
__global__ __launch_bounds__(256) __attribute__((amdgpu_waves_per_eu(2)))
void distgemm_kernel(const float* __restrict__ cat, int off,
                     const float* __restrict__ sq,
                     const float* __restrict__ XT,
                     float* __restrict__ D, int b0) {
    __shared__ float rows[16][K];
    int rb = blockIdx.x;
    int bl = rb / (NP / 16);
    int b = b0 + bl;
    int nb = (rb % (NP / 16)) * 16;
    int col = blockIdx.y * 1024 + threadIdx.x * 4;
    const float* src = cat + ((size_t)(b * NP + nb)) * CSTR + off;
    for (int e = threadIdx.x; e < 16 * (K / 4); e += 256) {
        int r = e / (K / 4), cg = e - r * (K / 4);
        *reinterpret_cast<float4*>(&rows[r][4 * cg]) =
            *reinterpret_cast<const float4*>(src + (size_t)r * CSTR + 4 * cg);
    }
    __syncthreads();
    const float* Wp = XT + (size_t)bl * K * NP;
    float acc[4][16];
    #pragma unroll
    for (int j = 0; j < 4; ++j)
        #pragma unroll
        for (int r = 0; r < 16; ++r) acc[j][r] = 0.f;
    for (int c = 0; c < K; c += 4) {
        float4 w0 = *reinterpret_cast<const float4*>(&Wp[(size_t)(c + 0) * NP + col]);
        float4 w1 = *reinterpret_cast<const float4*>(&Wp[(size_t)(c + 1) * NP + col]);
        float4 w2 = *reinterpret_cast<const float4*>(&Wp[(size_t)(c + 2) * NP + col]);
        float4 w3 = *reinterpret_cast<const float4*>(&Wp[(size_t)(c + 3) * NP + col]);
        #pragma unroll
        for (int r = 0; r < 16; ++r) {
            float4 rv = *reinterpret_cast<const float4*>(&rows[r][c]);
            acc[0][r] += rv.x * w0.x + rv.y * w1.x + rv.z * w2.x + rv.w * w3.x;
            acc[1][r] += rv.x * w0.y + rv.y * w1.y + rv.z * w2.y + rv.w * w3.y;
            acc[2][r] += rv.x * w0.z + rv.y * w1.z + rv.z * w2.z + rv.w * w3.z;
            acc[3][r] += rv.x * w0.w + rv.y * w1.w + rv.z * w2.w + rv.w * w3.w;
        }
    }
    float4 sqc = *reinterpret_cast<const float4*>(&sq[(size_t)b * NP + col]);
    float* drow = D + ((size_t)rb * 16) * NP + col;
    #pragma unroll
    for (int r = 0; r < 16; ++r) {
        float sqr = sq[(size_t)b * NP + nb + r];
        float4 outv = make_float4(2.f * acc[0][r] - sqr - sqc.x, 2.f * acc[1][r] - sqr - sqc.y,
                                  2.f * acc[2][r] - sqr - sqc.z, 2.f * acc[3][r] - sqr - sqc.w);
        *reinterpret_cast<float4*>(&drow[(size_t)r * NP]) = outv;
    }
}

// ---------------- top-k v2: register d[32] + selected-bitmask, no LDS ----------------
__global__ __launch_bounds__(256) void topk_kernel(const float* __restrict__ D,
                                                   int* __restrict__ idxout, int b0) {
    int wave = threadIdx.x >> 6, lane = threadIdx.x & 63;
    int ql = blockIdx.x * 4 + wave;
    const float* drow = D + (size_t)ql * NP;
    float d[32];
    #pragma unroll
    for (int t = 0; t < 32; ++t) d[t] = drow[t * 64 + lane];
    unsigned sel = 0;
    size_t q = (size_t)b0 * NP + ql;
    for (int k = 0; k < KNN; ++k) {
        float bv = -INFINITY; int bj = 0x7fffffff;
        #pragma unroll
        for (int t = 0; t < 32; ++t) {
            float v = (sel & (1u << t)) ? -INFINITY : d[t];
            if (v > bv) { bv = v; bj = t * 64 + lane; }
        }
        for (int s = 32; s; s >>= 1) {
            float ov = __shfl_xor(bv, s);
            int oj = __shfl_xor(bj, s);
            if (ov > bv || (ov == bv && oj < bj)) { bv = ov; bj = oj; }
        }
        if (lane == 0) idxout[q * KNN + k] = bj;
        if ((bj & 63) == lane) sel |= 1u << (bj >> 6);
    }
}

// ---------------- YZ GEMM: YZ[p][col0..col0+NO) = cat[p][0:K] @ Wyz ----------------
template <int K, int NT, int NO>
__global__ __launch_bounds__(NT) __attribute__((amdgpu_waves_per_eu(2)))
void gemm_yz_kernel(const float* __restrict__ cat, int off,
                    const float* __restrict__ W, int N2,
                    float* __restrict__ YZ) {
    __shared__ float rows[16][K];
    int col = (blockIdx.y * NT + threadIdx.x) * NO;
    const float* src = cat + (size_t)blockIdx.x * 16 * CSTR + off;
    for (int e = threadIdx.x; e < 16 * (K / 4); e += NT) {
        int r = e / (K / 4), cg = e - r * (K / 4);
        *reinterpret_cast<float4*>(&rows[r][4 * cg]) =
            *reinterpret_cast<const float4*>(src + (size_t)r * CSTR + 4 * cg);
    }
    __syncthreads();
    float acc[16][NO];
    #pragma unroll
    for (int r = 0; r < 16; ++r)
        #pragma unroll
        for (int j = 0; j < NO; ++j) acc[r][j] = 0.f;
    for (int c = 0; c < K; c += 4) {
        float wv[4][NO];
        #pragma unroll
        for (int i = 0; i < 4; ++i) {
            if constexpr (NO == 4) {
                float4 w = *reinterpret_cast<const float4*>(&W[(size_t)(c + i) * N2 + col]);
                wv[i][0] = w.x; wv[i][1] = w.y; wv[i][2] = w.z; wv[i][3] = w.w;
            } else if constexpr (NO == 2) {
                float2 w = *reinterpret_cast<const float2*>(&W[(size_t)(c + i) * N2 + col]);
                wv[i][0] = w.x; wv[i][1] = w.y;
            } else {
                wv[i][0] = W[(size_t)(c + i) * N2 + col];
            }
        }
        #pragma unroll
        for (int r = 0; r < 16; ++r) {
            float4 rv = *reinterpret_cast<const float4*>(&rows[r][c]);
            #pragma unroll
            for (int j = 0; j < NO; ++j)
                acc[r][j] += rv.x * wv[0][j] + rv.y * wv[1][j] + rv.z * wv[2][j] + rv.w * wv[3][j];
        }
    }
    #pragma unroll
    for (int r = 0; r < 16; ++r) {
        float* dst = YZ + ((size_t)blockIdx.x * 16 + r) * N2 + col;
        if constexpr (NO == 4) {
            *reinterpret_cast<float4*>(dst) = make_float4(acc[r][0], acc[r][1], acc[r][2], acc[r][3]);
        } else if constexpr (NO == 2) {
            *reinterpret_cast<float2*>(dst) = make_float2(acc[r][0], acc[r][1]);
        } else {
            dst[0] = acc[r][0];
        }
    }
}

// ---------------- combine: out[p][o] = max_k leaky((Y[j_k][o] + Z[p][o])*s + b) ----------------
template <int O>
__global__ __launch_bounds__(256) void combine_kernel(const float* __restrict__ YZ, int N2,
                                                      const int* __restrict__ idx,
                                                      const float* __restrict__ g,
                                                      const float* __restrict__ bias,
                                                      float* __restrict__ cat, int outOff) {
    constexpr int PPB = 256 / O;
    int sub = threadIdx.x / O, o = threadIdx.x % O;
    int p = blockIdx.x * PPB + sub;
    int bbase = p & ~(NP - 1);
    const float bns = 1.0f / sqrtf(1.0f + 1e-5f);
    float s = g[o] * bns, bo = bias[o];
    float z = YZ[(size_t)p * N2 + O + o];
    int js[KNN];
    #pragma unroll
    for (int k = 0; k < KNN; ++k) js[k] = idx[(size_t)p * KNN + k];
    float m = -INFINITY;
    #pragma unroll
    for (int k = 0; k < KNN; ++k) {
        float y = YZ[(size_t)(bbase + js[k]) * N2 + o];
        m = fmaxf(m, leaky((y + z) * s + bo));
    }
    cat[(size_t)p * CSTR + outOff + o] = m;
}

// ---------------- fused W5 matmul + pool, v6: v5 shape + amdgpu_waves_per_eu(2) ----------------
// 256 threads = 2 row-halves x 128 col-threads; block tile 16 x 1024; acc[8][8].
// waves_per_eu(2) raises the allocator's VGPR budget to ~256 so acc+weights stay resident
// (v3/v4/v5 all spilled ~100 floats/thread under the default 8-waves/EU budget).
__global__ __launch_bounds__(256) __attribute__((amdgpu_waves_per_eu(2)))
void pool_w5_kernel(const float* __restrict__ cat, const float* __restrict__ W5t,
                    const float* __restrict__ g5, const float* __restrict__ b5,
                    float* __restrict__ pmax, float* __restrict__ psum) {
    __shared__ float rows[16][CSTR];   // 33.3 KB
    int b = blockIdx.x >> 7, nc = blockIdx.x & 127;   // 128 chunks of 16 rows
    int ty = threadIdx.x >> 7;         // row half: rows ty*8 .. ty*8+7
    int tx = threadIdx.x & 127;
    int o8 = tx * 8;
    for (int e = threadIdx.x; e < 16 * (CSTR / 4); e += 256) {
        int r = e / (CSTR / 4), cg = e - r * (CSTR / 4);
        *reinterpret_cast<float4*>(&rows[r][4 * cg]) =
            *reinterpret_cast<const float4*>(&cat[((size_t)b * NP + nc * 16 + r) * CSTR + 4 * cg]);
    }
    __syncthreads();
    float acc[8][8];
    #pragma unroll
    for (int r = 0; r < 8; ++r)
        #pragma unroll
        for (int j = 0; j < 8; ++j) acc[r][j] = 0.f;
    const int r0 = ty * 8;
    for (int c = 0; c < CSTR; c += 4) {
        float4 wa0 = *reinterpret_cast<const float4*>(&W5t[(size_t)(c + 0) * 1024 + o8]);
        float4 wb0 = *reinterpret_cast<const float4*>(&W5t[(size_t)(c + 0) * 1024 + o8 + 4]);
        float4 wa1 = *reinterpret_cast<const float4*>(&W5t[(size_t)(c + 1) * 1024 + o8]);
        float4 wb1 = *reinterpret_cast<const float4*>(&W5t[(size_t)(c + 1) * 1024 + o8 + 4]);
        float4 wa2 = *reinterpret_cast<const float4*>(&W5t[(size_t)(c + 2) * 1024 + o8]);
        float4 wb2 = *reinterpret_cast<const float4*>(&W5t[(size_t)(c + 2) * 1024 + o8 + 4]);
        float4 wa3 = *reinterpret_cast<const float4*>(&W5t[(size_t)(c + 3) * 1024 + o8]);
        float4 wb3 = *reinterpret_cast<const float4*>(&W5t[(size_t)(c + 3) * 1024 + o8 + 4]);
        #pragma unroll
        for (int r = 0; r < 8; ++r) {
            float4 rv = *reinterpret_cast<const float4*>(&rows[r0 + r][c]);
            acc[r][0] += rv.x * wa0.x + rv.y * wa1.x + rv.z * wa2.x + rv.w * wa3.x;
            acc[r][1] += rv.x * wa0.y + rv.y * wa1.y + rv.z * wa2.y + rv.w * wa3.y;
            acc[r][2] += rv.x * wa0.z + rv.y * wa1.z + rv.z * wa2.z + rv.w * wa3.z;
            acc[r][3] += rv.x * wa0.w + rv.y * wa1.w + rv.z * wa2.w + rv.w * wa3.w;
            acc[r][4] += rv.x * wb0.x + rv.y * wb1.x + rv.z * wb2.x + rv.w * wb3.x;
            acc[r][5] += rv.x * wb0.y + rv.y * wb1.y + rv.z * wb2.y + rv.w * wb3.y;
            acc[r][6] += rv.x * wb0.z + rv.y * wb1.z + rv.z * wb2.z + rv.w * wb3.z;
            acc[r][7] += rv.x * wb0.w + rv.y * wb1.w + rv.z * wb2.w + rv.w * wb3.w;
        }
    }
    const float bns = 1.0f / sqrtf(1.0f + 1e-5f);
    int chunk = nc * 2 + ty;           // 256 chunks of 8 rows
    #pragma unroll
    for (int j = 0; j < 8; ++j) {
        float gs = g5[o8 + j] * bns, bo = b5[o8 + j];
        float vmax = -INFINITY, vsum = 0.f;
        #pragma unroll
        for (int r = 0; r < 8; ++r) {
            float v = leaky(acc[r][j] * gs + bo);
            vmax = fmaxf(vmax, v); vsum += v;
        }
        pmax[((size_t)b * 1024 + o8 + j) * 256 + chunk] = vmax;
        psum[((size_t)b * 1024 + o8 + j) * 256 + chunk] = vsum;
    }
}

__global__ void pool_reduce_kernel(const float* __restrict__ pmax, const float* __restrict__ psum,
                                   float* __restrict__ f0) {
    int i = blockIdx.x * blockDim.x + threadIdx.x;
    if (i >= NB * 1024) return;
    int b = i >> 10, o = i & 1023;
    float m = -INFINITY, sm = 0.f;
    for (int nc = 0; nc < 256; ++nc) { m = fmaxf(m, pmax[(size_t)i * 256 + nc]); sm += psum[(size_t)i * 256 + nc]; }
    f0[(size_t)b * 2048 + o] = m;
    f0[(size_t)b * 2048 + 1024 + o] = sm * (1.0f / 2048.0f);
}

// ---------------- dense: one thread per (b, o), float4 dot ----------------
__global__ void dense_kernel(const float* __restrict__ in, const float* __restrict__ W,
                             const float* __restrict__ bl, const float* __restrict__ g,
                             const float* __restrict__ bb, float* __restrict__ out,
                             int In, int Out, int act) {
    int i = blockIdx.x * blockDim.x + threadIdx.x;
    if (i >= NB * Out) return;
    int b = i / Out, o = i - b * Out;
    const float* w = W + (size_t)o * In;
    const float* xv = in + (size_t)b * In;
    float acc = 0.f;
    for (int c = 0; c < In; c += 4) {
        float4 a = *reinterpret_cast<const float4*>(&xv[c]);
        float4 v = *reinterpret_cast<const float4*>(&w[c]);
        acc += a.x * v.x + a.y * v.y + a.z * v.z + a.w * v.w;
    }
    acc += bl[o];
    if (act) {
        const float bns = 1.0f / sqrtf(1.0f + 1e-5f);
        acc = leaky(acc * (g[o] * bns) + bb[o]);
    }
    out[i] = acc;
}

extern "C" void kernel_launch(void* const* d_in, const int* in_sizes, int n_in,
                              void* d_out, int out_size, void* d_ws, size_t ws_size,
                              hipStream_t stream) {
    const float* x   = (const float*)d_in[0];
    const float* W1  = (const float*)d_in[2];
    const float* W2  = (const float*)d_in[3];
    const float* W3  = (const float*)d_in[4];
    const float* W4  = (const float*)d_in[5];
    const float* W5  = (const float*)d_in[6];
    const float* Wl1 = (const float*)d_in[7];
    const float* bl1 = (const float*)d_in[8];
    const float* Wl2 = (const float*)d_in[9];
    const float* bl2 = (const float*)d_in[10];
    const float* Wl3 = (const float*)d_in[11];
    const float* bl3 = (const float*)d_in[12];
    const float* g1 = (const float*)d_in[13]; const float* b1 = (const float*)d_in[14];
    const float* g2 = (const float*)d_in[15]; const float* b2 = (const float*)d_in[16];
    const float* g3 = (const float*)d_in[17]; const float* b3 = (const float*)d_in[18];
    const float* g4 = (const float*)d_in[19]; const float* b4 = (const float*)d_in[20];
    const float* g5 = (const float*)d_in[21]; const float* b5 = (const float*)d_in[22];
    const float* g6 = (const float*)d_in[23]; const float* bb6 = (const float*)d_in[24];
    const float* g7 = (const float*)d_in[25]; const float* bb7 = (const float*)d_in[26];

    float* ws = (float*)d_ws;
    size_t off = 0;
    float* CAT = ws + off; off += (size_t)NB * NP * CSTR;
    float* SQ  = ws + off; off += NB * NP;
    int*   IDX = (int*)(ws + off); off += (size_t)NB * NP * KNN;
    float* WYZ1 = ws + off; off += 4 * 128;
    float* WYZ2 = ws + off; off += 68 * 128;
    float* WYZ3 = ws + off; off += 132 * 256;
    float* WYZ4 = ws + off; off += 260 * 512;
    float* W5T = ws + off; off += 520 * 1024;
    float* BIG = ws + off;                    // shared region: DMAT+XT | YZ | pool buffers
    size_t wsfl = ws_size / 4;
    size_t avail = (wsfl > off) ? (wsfl - off) : 0;
    const size_t yzneed = (size_t)NB * NP * 512;
    int G = 1;
    for (int g = 8; g >= 1; g >>= 1) {
        size_t need = (size_t)g * NP * 2048 + (size_t)g * 128 * NP;   // DMAT + XT(K<=128)
        size_t big = (need > yzneed) ? need : yzneed;
        if (big <= avail) { G = g; break; }
    }
    float* DMAT = BIG;
    float* XT   = BIG + (size_t)G * NP * 2048;
    float* YZ   = BIG;
    float* PMAX = BIG;
    float* PSUM = PMAX + (size_t)NB * 1024 * 256;
    float* F0 = PSUM + (size_t)NB * 1024 * 256;
    float* F1 = F0 + NB * 2048;
    float* F2 = F1 + NB * 512;
    (void)in_sizes; (void)n_in; (void)out_size;

    dim3 b256(256);
    const int M16 = NB * NP / 16;   // 1024 row-blocks

    tx_kernel<<<(NB * NP + 255) / 256, b256, 0, stream>>>(x, CAT);
    buildWyz<<<(4 * 128 + 255) / 256, b256, 0, stream>>>(W1, WYZ1, 64, 3, 4);
    buildWyz<<<(68 * 128 + 255) / 256, b256, 0, stream>>>(W2, WYZ2, 64, 67, 68);
    buildWyz<<<(132 * 256 + 255) / 256, b256, 0, stream>>>(W3, WYZ3, 128, 131, 132);
    buildWyz<<<(260 * 512 + 255) / 256, b256, 0, stream>>>(W4, WYZ4, 256, 259, 260);
    transposeW5<<<(520 * 1024 + 255) / 256, b256, 0, stream>>>(W5, W5T);

#define RUN_KNN(KK, OFFC)                                                                   \
    do {                                                                                    \
        sqnorm_kernel<<<(NB * NP + 255) / 256, b256, 0, stream>>>(CAT, OFFC, KK, SQ);       \
        for (int b0 = 0; b0 < NB; b0 += G) {                                                \
            xt_kernel<KK><<<dim3(G, NP / 64), b256, 0, stream>>>(CAT, OFFC, XT, b0);        \
            distgemm_kernel<KK><<<dim3(G * (NP / 16), NP / 1024), b256, 0, stream>>>(       \
                CAT, OFFC, SQ, XT, DMAT, b0);                                               \
            topk_kernel<<<G * NP / 4, b256, 0, stream>>>(DMAT, IDX, b0);                    \
        }                                                                                   \
    } while (0)

    // layer 1
    RUN_KNN(4, 0);
    gemm_yz_kernel<4, 128, 1><<<dim3(M16, 1), 128, 0, stream>>>(CAT, 0, WYZ1, 128, YZ);
    combine_kernel<64><<<NB * NP / 4, b256, 0, stream>>>(YZ, 128, IDX, g1, b1, CAT, 4);
    // layer 2
    RUN_KNN(64, 4);
    gemm_yz_kernel<68, 128, 1><<<dim3(M16, 1), 128, 0, stream>>>(CAT, 0, WYZ2, 128, YZ);
    combine_kernel<64><<<NB * NP / 4, b256, 0, stream>>>(YZ, 128, IDX, g2, b2, CAT, 68);
    // layer 3
    RUN_KNN(64, 68);
    gemm_yz_kernel<132, 128, 2><<<dim3(M16, 1), 128, 0, stream>>>(CAT, 0, WYZ3, 256, YZ);
    combine_kernel<128><<<NB * NP / 2, b256, 0, stream>>>(YZ, 256, IDX, g3, b3, CAT, 132);
    // layer 4
    RUN_KNN(128, 132);
    gemm_yz_kernel<260, 128, 4><<<dim3(M16, 1), 128, 0, stream>>>(CAT, 0, WYZ4, 512, YZ);
    combine_kernel<256><<<NB * NP, b256, 0, stream>>>(YZ, 512, IDX, g4, b4, CAT, 260);
#undef RUN_KNN

    // W5 + bn + leaky + global max/mean pool
    pool_w5_kernel<<<NB * 128, b256, 0, stream>>>(CAT, W5T, g5, b5, PMAX, PSUM);
    pool_reduce_kernel<<<(NB * 1024 + 255) / 256, b256, 0, stream>>>(PMAX, PSUM, F0);

    // MLP head
    dense_kernel<<<(NB * 512 + 255) / 256, b256, 0, stream>>>(F0, Wl1, bl1, g6, bb6, F1, 2048, 512, 1);
    dense_kernel<<<(NB * 256 + 255) / 256, b256, 0, stream>>>(F1, Wl2, bl2, g7, bb7, F2, 512, 256, 1);
    dense_kernel<<<(NB * 40 + 255) / 256, b256, 0, stream>>>(F2, Wl3, bl3, nullptr, nullptr,
                                                             (float*)d_out, 256, 40, 0);
}

// Round 12
// 1379.717 us; speedup vs baseline: 23.2820x; 1.0199x over previous
//
#include <hip/hip_runtime.h>
#include <math.h>

#define NB 8
#define NP 2048
#define KNN 20
#define CSTR 520          // padded row stride of the cat feature buffer (floats)
#define NEG 0.2f
// padded column layout: [x:0..3)[pad:3][x1:4..68)[x2:68..132)[x3:132..260)[x4:260..516)

__device__ __forceinline__ float leaky(float x) { return x >= 0.0f ? x : NEG * x; }

// ---------------- transpose x (B,3,N) -> cat[:, :, 0:3], zero pad col 3 ----------------
__global__ void tx_kernel(const float* __restrict__ x, float* __restrict__ cat) {
    int i = blockIdx.x * blockDim.x + threadIdx.x;
    if (i >= NB * NP) return;
    int b = i / NP, n = i % NP;
    float* r = cat + (size_t)i * CSTR;
    r[0] = x[((size_t)b * 3 + 0) * NP + n];
    r[1] = x[((size_t)b * 3 + 1) * NP + n];
    r[2] = x[((size_t)b * 3 + 2) * NP + n];
    r[3] = 0.0f;
    r[516] = 0.f; r[517] = 0.f; r[518] = 0.f; r[519] = 0.f;
}

// ---------------- conv weights W (O, 2*Cin) -> Wyz (PC, 2*O): [Wd | Wc - Wd] ----------------
__global__ void buildWyz(const float* __restrict__ W, float* __restrict__ Wyz,
                         int O, int Cin, int PC) {
    int i = blockIdx.x * blockDim.x + threadIdx.x;
    int N2 = 2 * O;
    if (i >= PC * N2) return;
    int q = i / N2, n = i - q * N2;
    float v = 0.0f;
    if (q != 3) {
        int c = (q < 3) ? q : q - 1;
        if (c < Cin) {
            int o = (n < O) ? n : n - O;
            float wd = W[(size_t)o * (2 * Cin) + c];
            v = (n < O) ? wd : (W[(size_t)o * (2 * Cin) + Cin + c] - wd);
        }
    }
    Wyz[i] = v;
}

// ---------------- W5 (1024, 515) -> padded transposed W5t (520, 1024) ----------------
__global__ void transposeW5(const float* __restrict__ W, float* __restrict__ Wt) {
    int i = blockIdx.x * blockDim.x + threadIdx.x;
    if (i >= 520 * 1024) return;
    int p = i >> 10, o = i & 1023;
    float v = 0.0f;
    if (p < 516 && p != 3) {
        int c = (p < 3) ? p : p - 1;
        v = W[(size_t)o * 515 + c];
    }
    Wt[i] = v;
}

// ---------------- squared norms of feature slice (padded C, pad col is zero) ----------------
__global__ void sqnorm_kernel(const float* __restrict__ cat, int off, int C, float* __restrict__ sq) {
    int i = blockIdx.x * blockDim.x + threadIdx.x;
    if (i >= NB * NP) return;
    const float* f = cat + (size_t)i * CSTR + off;
    float s = 0.f;
    for (int c = 0; c < C; c += 4) {
        float4 v = *reinterpret_cast<const float4*>(f + c);
        s += v.x * v.x + v.y * v.y + v.z * v.z + v.w * v.w;
    }
    sq[i] = s;
}

// ---------------- XT: slice transpose cat[b][n][off+c] -> XT[bl][c][n] ----------------
template <int K>
__global__ void __launch_bounds__(256) xt_kernel(const float* __restrict__ cat, int off,
                                                 float* __restrict__ XT, int b0) {
    __shared__ float lds[64][K + 1];
    int bl = blockIdx.x;
    int b = b0 + bl;
    int n0 = blockIdx.y * 64;
    const float* src = cat + ((size_t)(b * NP + n0)) * CSTR + off;
    for (int e = threadIdx.x; e < 64 * (K / 4); e += 256) {
        int r = e / (K / 4), cg = e - r * (K / 4);
        float4 v = *reinterpret_cast<const float4*>(src + (size_t)r * CSTR + 4 * cg);
        lds[r][4 * cg + 0] = v.x; lds[r][4 * cg + 1] = v.y;
        lds[r][4 * cg + 2] = v.z; lds[r][4 * cg + 3] = v.w;
    }
    __syncthreads();
    float* dst = XT + (size_t)bl * K * NP;
    for (int e = threadIdx.x; e < 64 * K; e += 256) {
        int c = e >> 6, tn = e & 63;
        dst[(size_t)c * NP + n0 + tn] = lds[tn][c];
    }
}

// ---------------- distance GEMM v4: 16-row x 4-col blocking, min-waves 2 (VGPR cap 256) ----------------
template <int K>
__global__ void __launch_bounds__(256, 2)
distgemm_kernel(const float* __restrict__ cat, int off,
                const float* __restrict__ sq,
                const float* __restrict__ XT,
                float* __restrict__ D, int b0) {
    __shared__ float rows[16][K];
    int rb = blockIdx.x;
    int bl = rb / (NP / 16);
    int b = b0 + bl;
    int nb = (rb % (NP / 16)) * 16;
    int col = blockIdx.y * 1024 + threadIdx.x * 4;
    const float* src = cat + ((size_t)(b * NP + nb)) * CSTR + off;
    for (int e = threadIdx.x; e < 16 * (K / 4); e += 256) {
        int r = e / (K / 4), cg = e - r * (K / 4);
        *reinterpret_cast<float4*>(&rows[r][4 * cg]) =
            *reinterpret_cast<const float4*>(src + (size_t)r * CSTR + 4 * cg);
    }
    __syncthreads();
    const float* Wp = XT + (size_t)bl * K * NP;
    float acc[4][16];
    #pragma unroll
    for (int j = 0; j < 4; ++j)
        #pragma unroll
        for (int r = 0; r < 16; ++r) acc[j][r] = 0.f;
    for (int c = 0; c < K; c += 4) {
        float4 w0 = *reinterpret_cast<const float4*>(&Wp[(size_t)(c + 0) * NP + col]);
        float4 w1 = *reinterpret_cast<const float4*>(&Wp[(size_t)(c + 1) * NP + col]);
        float4 w2 = *reinterpret_cast<const float4*>(&Wp[(size_t)(c + 2) * NP + col]);
        float4 w3 = *reinterpret_cast<const float4*>(&Wp[(size_t)(c + 3) * NP + col]);
        #pragma unroll
        for (int r = 0; r < 16; ++r) {
            float4 rv = *reinterpret_cast<const float4*>(&rows[r][c]);
            acc[0][r] += rv.x * w0.x + rv.y * w1.x + rv.z * w2.x + rv.w * w3.x;
            acc[1][r] += rv.x * w0.y + rv.y * w1.y + rv.z * w2.y + rv.w * w3.y;
            acc[2][r] += rv.x * w0.z + rv.y * w1.z + rv.z * w2.z + rv.w * w3.z;
            acc[3][r] += rv.x * w0.w + rv.y * w1.w + rv.z * w2.w + rv.w * w3.w;
        }
    }
    float4 sqc = *reinterpret_cast<const float4*>(&sq[(size_t)b * NP + col]);
    float* drow = D + ((size_t)rb * 16) * NP + col;
    #pragma unroll
    for (int r = 0; r < 16; ++r) {
        float sqr = sq[(size_t)b * NP + nb + r];
        float4 outv = make_float4(2.f * acc[0][r] - sqr - sqc.x, 2.f * acc[1][r] - sqr - sqc.y,
                                  2.f * acc[2][r] - sqr - sqc.z, 2.f * acc[3][r] - sqr - sqc.w);
        *reinterpret_cast<float4*>(&drow[(size_t)r * NP]) = outv;
    }
}

// ---------------- top-k v2: register d[32] + selected-bitmask, no LDS ----------------
__global__ void __launch_bounds__(256) topk_kernel(const float* __restrict__ D,
                                                   int* __restrict__ idxout, int b0) {
    int wave = threadIdx.x >> 6, lane = threadIdx.x & 63;
    int ql = blockIdx.x * 4 + wave;
    const float* drow = D + (size_t)ql * NP;
    float d[32];
    #pragma unroll
    for (int t = 0; t < 32; ++t) d[t] = drow[t * 64 + lane];
    unsigned sel = 0;
    size_t q = (size_t)b0 * NP + ql;
    for (int k = 0; k < KNN; ++k) {
        float bv = -INFINITY; int bj = 0x7fffffff;
        #pragma unroll
        for (int t = 0; t < 32; ++t) {
            float v = (sel & (1u << t)) ? -INFINITY : d[t];
            if (v > bv) { bv = v; bj = t * 64 + lane; }
        }
        for (int s = 32; s; s >>= 1) {
            float ov = __shfl_xor(bv, s);
            int oj = __shfl_xor(bj, s);
            if (ov > bv || (ov == bv && oj < bj)) { bv = ov; bj = oj; }
        }
        if (lane == 0) idxout[q * KNN + k] = bj;
        if ((bj & 63) == lane) sel |= 1u << (bj >> 6);
    }
}

// ---------------- YZ GEMM: YZ[p][col0..col0+NO) = cat[p][0:K] @ Wyz ----------------
template <int K, int NT, int NO>
__global__ void __launch_bounds__(NT, 2)
gemm_yz_kernel(const float* __restrict__ cat, int off,
               const float* __restrict__ W, int N2,
               float* __restrict__ YZ) {
    __shared__ float rows[16][K];
    int col = (blockIdx.y * NT + threadIdx.x) * NO;
    const float* src = cat + (size_t)blockIdx.x * 16 * CSTR + off;
    for (int e = threadIdx.x; e < 16 * (K / 4); e += NT) {
        int r = e / (K / 4), cg = e - r * (K / 4);
        *reinterpret_cast<float4*>(&rows[r][4 * cg]) =
            *reinterpret_cast<const float4*>(src + (size_t)r * CSTR + 4 * cg);
    }
    __syncthreads();
    float acc[16][NO];
    #pragma unroll
    for (int r = 0; r < 16; ++r)
        #pragma unroll
        for (int j = 0; j < NO; ++j) acc[r][j] = 0.f;
    for (int c = 0; c < K; c += 4) {
        float wv[4][NO];
        #pragma unroll
        for (int i = 0; i < 4; ++i) {
            if constexpr (NO == 4) {
                float4 w = *reinterpret_cast<const float4*>(&W[(size_t)(c + i) * N2 + col]);
                wv[i][0] = w.x; wv[i][1] = w.y; wv[i][2] = w.z; wv[i][3] = w.w;
            } else if constexpr (NO == 2) {
                float2 w = *reinterpret_cast<const float2*>(&W[(size_t)(c + i) * N2 + col]);
                wv[i][0] = w.x; wv[i][1] = w.y;
            } else {
                wv[i][0] = W[(size_t)(c + i) * N2 + col];
            }
        }
        #pragma unroll
        for (int r = 0; r < 16; ++r) {
            float4 rv = *reinterpret_cast<const float4*>(&rows[r][c]);
            #pragma unroll
            for (int j = 0; j < NO; ++j)
                acc[r][j] += rv.x * wv[0][j] + rv.y * wv[1][j] + rv.z * wv[2][j] + rv.w * wv[3][j];
        }
    }
    #pragma unroll
    for (int r = 0; r < 16; ++r) {
        float* dst = YZ + ((size_t)blockIdx.x * 16 + r) * N2 + col;
        if constexpr (NO == 4) {
            *reinterpret_cast<float4*>(dst) = make_float4(acc[r][0], acc[r][1], acc[r][2], acc[r][3]);
        } else if constexpr (NO == 2) {
            *reinterpret_cast<float2*>(dst) = make_float2(acc[r][0], acc[r][1]);
        } else {
            dst[0] = acc[r][0];
        }
    }
}

// ---------------- combine: out[p][o] = max_k leaky((Y[j_k][o] + Z[p][o])*s + b) ----------------
template <int O>
__global__ void __launch_bounds__(256) combine_kernel(const float* __restrict__ YZ, int N2,
                                                      const int* __restrict__ idx,
                                                      const float* __restrict__ g,
                                                      const float* __restrict__ bias,
                                                      float* __restrict__ cat, int outOff) {
    constexpr int PPB = 256 / O;
    int sub = threadIdx.x / O, o = threadIdx.x % O;
    int p = blockIdx.x * PPB + sub;
    int bbase = p & ~(NP - 1);
    const float bns = 1.0f / sqrtf(1.0f + 1e-5f);
    float s = g[o] * bns, bo = bias[o];
    float z = YZ[(size_t)p * N2 + O + o];
    int js[KNN];
    #pragma unroll
    for (int k = 0; k < KNN; ++k) js[k] = idx[(size_t)p * KNN + k];
    float m = -INFINITY;
    #pragma unroll
    for (int k = 0; k < KNN; ++k) {
        float y = YZ[(size_t)(bbase + js[k]) * N2 + o];
        m = fmaxf(m, leaky((y + z) * s + bo));
    }
    cat[(size_t)p * CSTR + outOff + o] = m;
}

// ---------------- fused W5 matmul + pool, v7: v5 shape + launch_bounds(256,2) ----------------
// min 2 waves/EU -> VGPR cap ~256: acc[8][8] + 32 weight regs stay resident (v3-v6 spilled
// under the default 8-waves/EU 64-VGPR budget). PMAX/PSUM now [chunk][o]-major: each thread
// stores 2x float4 contiguous -> wave-coalesced, no 64B-line write amplification.
__global__ void __launch_bounds__(256, 2)
pool_w5_kernel(const float* __restrict__ cat, const float* __restrict__ W5t,
               const float* __restrict__ g5, const float* __restrict__ b5,
               float* __restrict__ pmax, float* __restrict__ psum) {
    __shared__ float rows[16][CSTR];   // 33.3 KB
    int b = blockIdx.x >> 7, nc = blockIdx.x & 127;   // 128 chunks of 16 rows
    int ty = threadIdx.x >> 7;         // row half: rows ty*8 .. ty*8+7
    int tx = threadIdx.x & 127;
    int o8 = tx * 8;
    for (int e = threadIdx.x; e < 16 * (CSTR / 4); e += 256) {
        int r = e / (CSTR / 4), cg = e - r * (CSTR / 4);
        *reinterpret_cast<float4*>(&rows[r][4 * cg]) =
            *reinterpret_cast<const float4*>(&cat[((size_t)b * NP + nc * 16 + r) * CSTR + 4 * cg]);
    }
    __syncthreads();
    float acc[8][8];
    #pragma unroll
    for (int r = 0; r < 8; ++r)
        #pragma unroll
        for (int j = 0; j < 8; ++j) acc[r][j] = 0.f;
    const int r0 = ty * 8;
    for (int c = 0; c < CSTR; c += 4) {
        float4 wa0 = *reinterpret_cast<const float4*>(&W5t[(size_t)(c + 0) * 1024 + o8]);
        float4 wb0 = *reinterpret_cast<const float4*>(&W5t[(size_t)(c + 0) * 1024 + o8 + 4]);
        float4 wa1 = *reinterpret_cast<const float4*>(&W5t[(size_t)(c + 1) * 1024 + o8]);
        float4 wb1 = *reinterpret_cast<const float4*>(&W5t[(size_t)(c + 1) * 1024 + o8 + 4]);
        float4 wa2 = *reinterpret_cast<const float4*>(&W5t[(size_t)(c + 2) * 1024 + o8]);
        float4 wb2 = *reinterpret_cast<const float4*>(&W5t[(size_t)(c + 2) * 1024 + o8 + 4]);
        float4 wa3 = *reinterpret_cast<const float4*>(&W5t[(size_t)(c + 3) * 1024 + o8]);
        float4 wb3 = *reinterpret_cast<const float4*>(&W5t[(size_t)(c + 3) * 1024 + o8 + 4]);
        #pragma unroll
        for (int r = 0; r < 8; ++r) {
            float4 rv = *reinterpret_cast<const float4*>(&rows[r0 + r][c]);
            acc[r][0] += rv.x * wa0.x + rv.y * wa1.x + rv.z * wa2.x + rv.w * wa3.x;
            acc[r][1] += rv.x * wa0.y + rv.y * wa1.y + rv.z * wa2.y + rv.w * wa3.y;
            acc[r][2] += rv.x * wa0.z + rv.y * wa1.z + rv.z * wa2.z + rv.w * wa3.z;
            acc[r][3] += rv.x * wa0.w + rv.y * wa1.w + rv.z * wa2.w + rv.w * wa3.w;
            acc[r][4] += rv.x * wb0.x + rv.y * wb1.x + rv.z * wb2.x + rv.w * wb3.x;
            acc[r][5] += rv.x * wb0.y + rv.y * wb1.y + rv.z * wb2.y + rv.w * wb3.y;
            acc[r][6] += rv.x * wb0.z + rv.y * wb1.z + rv.z * wb2.z + rv.w * wb3.z;
            acc[r][7] += rv.x * wb0.w + rv.y * wb1.w + rv.z * wb2.w + rv.w * wb3.w;
        }
    }
    const float bns = 1.0f / sqrtf(1.0f + 1e-5f);
    int chunk = nc * 2 + ty;           // 256 chunks of 8 rows
    float pm[8], ps[8];
    #pragma unroll
    for (int j = 0; j < 8; ++j) {
        float gs = g5[o8 + j] * bns, bo = b5[o8 + j];
        float vmax = -INFINITY, vsum = 0.f;
        #pragma unroll
        for (int r = 0; r < 8; ++r) {
            float v = leaky(acc[r][j] * gs + bo);
            vmax = fmaxf(vmax, v); vsum += v;
        }
        pm[j] = vmax; ps[j] = vsum;
    }
    float* pmx = pmax + ((size_t)b * 256 + chunk) * 1024 + o8;
    float* psx = psum + ((size_t)b * 256 + chunk) * 1024 + o8;
    *reinterpret_cast<float4*>(pmx)     = make_float4(pm[0], pm[1], pm[2], pm[3]);
    *reinterpret_cast<float4*>(pmx + 4) = make_float4(pm[4], pm[5], pm[6], pm[7]);
    *reinterpret_cast<float4*>(psx)     = make_float4(ps[0], ps[1], ps[2], ps[3]);
    *reinterpret_cast<float4*>(psx + 4) = make_float4(ps[4], ps[5], ps[6], ps[7]);
}

__global__ void pool_reduce_kernel(const float* __restrict__ pmax, const float* __restrict__ psum,
                                   float* __restrict__ f0) {
    int i = blockIdx.x * blockDim.x + threadIdx.x;
    if (i >= NB * 1024) return;
    int b = i >> 10, o = i & 1023;
    float m = -INFINITY, sm = 0.f;
    for (int nc = 0; nc < 256; ++nc) {
        m = fmaxf(m, pmax[((size_t)b * 256 + nc) * 1024 + o]);
        sm += psum[((size_t)b * 256 + nc) * 1024 + o];
    }
    f0[(size_t)b * 2048 + o] = m;
    f0[(size_t)b * 2048 + 1024 + o] = sm * (1.0f / 2048.0f);
}

// ---------------- dense: one thread per (b, o), float4 dot ----------------
__global__ void dense_kernel(const float* __restrict__ in, const float* __restrict__ W,
                             const float* __restrict__ bl, const float* __restrict__ g,
                             const float* __restrict__ bb, float* __restrict__ out,
                             int In, int Out, int act) {
    int i = blockIdx.x * blockDim.x + threadIdx.x;
    if (i >= NB * Out) return;
    int b = i / Out, o = i - b * Out;
    const float* w = W + (size_t)o * In;
    const float* xv = in + (size_t)b * In;
    float acc = 0.f;
    for (int c = 0; c < In; c += 4) {
        float4 a = *reinterpret_cast<const float4*>(&xv[c]);
        float4 v = *reinterpret_cast<const float4*>(&w[c]);
        acc += a.x * v.x + a.y * v.y + a.z * v.z + a.w * v.w;
    }
    acc += bl[o];
    if (act) {
        const float bns = 1.0f / sqrtf(1.0f + 1e-5f);
        acc = leaky(acc * (g[o] * bns) + bb[o]);
    }
    out[i] = acc;
}

extern "C" void kernel_launch(void* const* d_in, const int* in_sizes, int n_in,
                              void* d_out, int out_size, void* d_ws, size_t ws_size,
                              hipStream_t stream) {
    const float* x   = (const float*)d_in[0];
    const float* W1  = (const float*)d_in[2];
    const float* W2  = (const float*)d_in[3];
    const float* W3  = (const float*)d_in[4];
    const float* W4  = (const float*)d_in[5];
    const float* W5  = (const float*)d_in[6];
    const float* Wl1 = (const float*)d_in[7];
    const float* bl1 = (const float*)d_in[8];
    const float* Wl2 = (const float*)d_in[9];
    const float* bl2 = (const float*)d_in[10];
    const float* Wl3 = (const float*)d_in[11];
    const float* bl3 = (const float*)d_in[12];
    const float* g1 = (const float*)d_in[13]; const float* b1 = (const float*)d_in[14];
    const float* g2 = (const float*)d_in[15]; const float* b2 = (const float*)d_in[16];
    const float* g3 = (const float*)d_in[17]; const float* b3 = (const float*)d_in[18];
    const float* g4 = (const float*)d_in[19]; const float* b4 = (const float*)d_in[20];
    const float* g5 = (const float*)d_in[21]; const float* b5 = (const float*)d_in[22];
    const float* g6 = (const float*)d_in[23]; const float* bb6 = (const float*)d_in[24];
    const float* g7 = (const float*)d_in[25]; const float* bb7 = (const float*)d_in[26];

    float* ws = (float*)d_ws;
    size_t off = 0;
    float* CAT = ws + off; off += (size_t)NB * NP * CSTR;
    float* SQ  = ws + off; off += NB * NP;
    int*   IDX = (int*)(ws + off); off += (size_t)NB * NP * KNN;
    float* WYZ1 = ws + off; off += 4 * 128;
    float* WYZ2 = ws + off; off += 68 * 128;
    float* WYZ3 = ws + off; off += 132 * 256;
    float* WYZ4 = ws + off; off += 260 * 512;
    float* W5T = ws + off; off += 520 * 1024;
    float* BIG = ws + off;                    // shared region: DMAT+XT | YZ | pool buffers
    size_t wsfl = ws_size / 4;
    size_t avail = (wsfl > off) ? (wsfl - off) : 0;
    const size_t yzneed = (size_t)NB * NP * 512;
    int G = 1;
    for (int g = 8; g >= 1; g >>= 1) {
        size_t need = (size_t)g * NP * 2048 + (size_t)g * 128 * NP;   // DMAT + XT(K<=128)
        size_t big = (need > yzneed) ? need : yzneed;
        if (big <= avail) { G = g; break; }
    }
    float* DMAT = BIG;
    float* XT   = BIG + (size_t)G * NP * 2048;
    float* YZ   = BIG;
    float* PMAX = BIG;
    float* PSUM = PMAX + (size_t)NB * 256 * 1024;
    float* F0 = PSUM + (size_t)NB * 256 * 1024;
    float* F1 = F0 + NB * 2048;
    float* F2 = F1 + NB * 512;
    (void)in_sizes; (void)n_in; (void)out_size;

    dim3 b256(256);
    const int M16 = NB * NP / 16;   // 1024 row-blocks

    tx_kernel<<<(NB * NP + 255) / 256, b256, 0, stream>>>(x, CAT);
    buildWyz<<<(4 * 128 + 255) / 256, b256, 0, stream>>>(W1, WYZ1, 64, 3, 4);
    buildWyz<<<(68 * 128 + 255) / 256, b256, 0, stream>>>(W2, WYZ2, 64, 67, 68);
    buildWyz<<<(132 * 256 + 255) / 256, b256, 0, stream>>>(W3, WYZ3, 128, 131, 132);
    buildWyz<<<(260 * 512 + 255) / 256, b256, 0, stream>>>(W4, WYZ4, 256, 259, 260);
    transposeW5<<<(520 * 1024 + 255) / 256, b256, 0, stream>>>(W5, W5T);

#define RUN_KNN(KK, OFFC)                                                                   \
    do {                                                                                    \
        sqnorm_kernel<<<(NB * NP + 255) / 256, b256, 0, stream>>>(CAT, OFFC, KK, SQ);       \
        for (int b0 = 0; b0 < NB; b0 += G) {                                                \
            xt_kernel<KK><<<dim3(G, NP / 64), b256, 0, stream>>>(CAT, OFFC, XT, b0);        \
            distgemm_kernel<KK><<<dim3(G * (NP / 16), NP / 1024), b256, 0, stream>>>(       \
                CAT, OFFC, SQ, XT, DMAT, b0);                                               \
            topk_kernel<<<G * NP / 4, b256, 0, stream>>>(DMAT, IDX, b0);                    \
        }                                                                                   \
    } while (0)

    // layer 1
    RUN_KNN(4, 0);
    gemm_yz_kernel<4, 128, 1><<<dim3(M16, 1), 128, 0, stream>>>(CAT, 0, WYZ1, 128, YZ);
    combine_kernel<64><<<NB * NP / 4, b256, 0, stream>>>(YZ, 128, IDX, g1, b1, CAT, 4);
    // layer 2
    RUN_KNN(64, 4);
    gemm_yz_kernel<68, 128, 1><<<dim3(M16, 1), 128, 0, stream>>>(CAT, 0, WYZ2, 128, YZ);
    combine_kernel<64><<<NB * NP / 4, b256, 0, stream>>>(YZ, 128, IDX, g2, b2, CAT, 68);
    // layer 3
    RUN_KNN(64, 68);
    gemm_yz_kernel<132, 128, 2><<<dim3(M16, 1), 128, 0, stream>>>(CAT, 0, WYZ3, 256, YZ);
    combine_kernel<128><<<NB * NP / 2, b256, 0, stream>>>(YZ, 256, IDX, g3, b3, CAT, 132);
    // layer 4
    RUN_KNN(128, 132);
    gemm_yz_kernel<260, 128, 4><<<dim3(M16, 1), 128, 0, stream>>>(CAT, 0, WYZ4, 512, YZ);
    combine_kernel<256><<<NB * NP, b256, 0, stream>>>(YZ, 512, IDX, g4, b4, CAT, 260);
#undef RUN_KNN

    // W5 + bn + leaky + global max/mean pool
    pool_w5_kernel<<<NB * 128, b256, 0, stream>>>(CAT, W5T, g5, b5, PMAX, PSUM);
    pool_reduce_kernel<<<(NB * 1024 + 255) / 256, b256, 0, stream>>>(PMAX, PSUM, F0);

    // MLP head
    dense_kernel<<<(NB * 512 + 255) / 256, b256, 0, stream>>>(F0, Wl1, bl1, g6, bb6, F1, 2048, 512, 1);
    dense_kernel<<<(NB * 256 + 255) / 256, b256, 0, stream>>>(F1, Wl2, bl2, g7, bb7, F2, 512, 256, 1);
    dense_kernel<<<(NB * 40 + 255) / 256, b256, 0, stream>>>(F2, Wl3, bl3, nullptr, nullptr,
                                                             (float*)d_out, 256, 40, 0);
}